// Round 18
// baseline (285.415 us; speedup 1.0000x reference)
//
#include <hip/hip_runtime.h>
#include <math.h>

constexpr int NPTS  = 8192;
constexpr int HIDC  = 128;
constexpr int OUTC2 = 256;
constexpr int PQC   = 512;
constexpr int KK1   = 16;
constexpr int KK2   = 8;

typedef __attribute__((ext_vector_type(8))) short short8;
typedef __attribute__((ext_vector_type(4))) float f32x4;

__device__ __forceinline__ f32x4 mfma16(short8 a, short8 b, f32x4 c) {
  return __builtin_amdgcn_mfma_f32_16x16x32_bf16(a, b, c, 0, 0, 0);
}

__device__ __forceinline__ void async_ld16(void* lds, const void* g) {
  __builtin_amdgcn_global_load_lds(
      (const __attribute__((address_space(1))) unsigned int*)g,
      (__attribute__((address_space(3))) unsigned int*)lds, 16, 0, 0);
}

#define CEU(a, b) { unsigned _t = (a) < (b) ? (a) : (b); (b) = (a) < (b) ? (b) : (a); (a) = _t; }

// guarded bitonic halver + 12-CE merge: kk asc, b asc -> kk = smallest-8 asc.
__device__ __forceinline__ void topk8_merge_sorted(unsigned (&kk)[KK2], unsigned (&b)[KK2]) {
  if (b[0] < kk[7]) {
    kk[0] = kk[0] < b[7] ? kk[0] : b[7];
    kk[1] = kk[1] < b[6] ? kk[1] : b[6];
    kk[2] = kk[2] < b[5] ? kk[2] : b[5];
    kk[3] = kk[3] < b[4] ? kk[3] : b[4];
    kk[4] = kk[4] < b[3] ? kk[4] : b[3];
    kk[5] = kk[5] < b[2] ? kk[5] : b[2];
    kk[6] = kk[6] < b[1] ? kk[6] : b[1];
    kk[7] = kk[7] < b[0] ? kk[7] : b[0];
    CEU(kk[0], kk[4]); CEU(kk[1], kk[5]); CEU(kk[2], kk[6]); CEU(kk[3], kk[7]);
    CEU(kk[0], kk[2]); CEU(kk[1], kk[3]); CEU(kk[4], kk[6]); CEU(kk[5], kk[7]);
    CEU(kk[0], kk[1]); CEU(kk[2], kk[3]); CEU(kk[4], kk[5]); CEU(kk[6], kk[7]);
  }
}

// Batcher OEM-8 sort (19 CE) then guarded merge. Exact top-8 SET (unique keys).
__device__ __forceinline__ void topk8_batch8(unsigned (&kk)[KK2], unsigned (&b)[KK2]) {
  CEU(b[0], b[1]); CEU(b[2], b[3]); CEU(b[4], b[5]); CEU(b[6], b[7]);
  CEU(b[0], b[2]); CEU(b[1], b[3]); CEU(b[4], b[6]); CEU(b[5], b[7]);
  CEU(b[1], b[2]); CEU(b[5], b[6]);
  CEU(b[0], b[4]); CEU(b[1], b[5]); CEU(b[2], b[6]); CEU(b[3], b[7]);
  CEU(b[2], b[4]); CEU(b[3], b[5]);
  CEU(b[1], b[2]); CEU(b[3], b[4]); CEU(b[5], b[6]);
  topk8_merge_sorted(kk, b);
}

// sort4 + guarded halver (R17-validated).
__device__ __forceinline__ void topk8_batch4(unsigned (&kk)[KK2],
                                             unsigned b0, unsigned b1,
                                             unsigned b2, unsigned b3) {
  CEU(b0, b1); CEU(b2, b3); CEU(b0, b2); CEU(b1, b3); CEU(b1, b2);
  if (b0 < kk[7]) {
    kk[4] = kk[4] < b3 ? kk[4] : b3;
    kk[5] = kk[5] < b2 ? kk[5] : b2;
    kk[6] = kk[6] < b1 ? kk[6] : b1;
    kk[7] = kk[7] < b0 ? kk[7] : b0;
    CEU(kk[0], kk[4]); CEU(kk[1], kk[5]); CEU(kk[2], kk[6]); CEU(kk[3], kk[7]);
    CEU(kk[0], kk[2]); CEU(kk[1], kk[3]); CEU(kk[4], kk[6]); CEU(kk[5], kk[7]);
    CEU(kk[0], kk[1]); CEU(kk[2], kk[3]); CEU(kk[4], kk[5]); CEU(kk[6], kk[7]);
  }
}

// lexicographic (d, idx) insert — exact fp32 merging.
template <int K>
__device__ __forceinline__ void ins_lex(float (&kf)[K], int (&ki)[K], float v, int j) {
  bool ins = (v < kf[K - 1]) || (v == kf[K - 1] && j < ki[K - 1]);
  if (ins) {
    kf[K - 1] = v; ki[K - 1] = j;
    #pragma unroll
    for (int p = K - 1; p > 0; --p) {
      float fa = kf[p - 1], fb = kf[p];
      int   ia = ki[p - 1], ib = ki[p];
      bool sw = (fb < fa) || (fb == fa && ib < ia);
      kf[p - 1] = sw ? fb : fa; ki[p - 1] = sw ? ib : ia;
      kf[p]     = sw ? fa : fb; ki[p]     = sw ? ia : ib;
    }
  }
}

__device__ __forceinline__ unsigned short bf16_rn(float x) {
  unsigned int u = __float_as_uint(x);
  unsigned int r = u + 0x7fffu + ((u >> 16) & 1u);
  return (unsigned short)(r >> 16);
}

// ---------------------------------------------------------------- pack x
__global__ void pack_x_kernel(const float* __restrict__ x, float4* __restrict__ x4) {
  int i = blockIdx.x * blockDim.x + threadIdx.x;
  if (i < NPTS) {
    float a = x[3 * i], b = x[3 * i + 1], c = x[3 * i + 2];
    x4[i] = make_float4(a, b, c, a * a + b * b + c * c);
  }
}

// ---------------------------------------------------------------- merged weight prep
// blocks 0..255: WcF (Wl-Wh | Wh), 256..383: W1bF, 384..639: W2F
__global__ void prep_weights_kernel(
    const float* __restrict__ W2a, const float* __restrict__ W1b,
    const float* __restrict__ W2b,
    unsigned short* __restrict__ WcFhi, unsigned short* __restrict__ WcFlo,
    unsigned short* __restrict__ W1bFhi, unsigned short* __restrict__ W1bFlo,
    unsigned short* __restrict__ W2Fhi, unsigned short* __restrict__ W2Flo) {
  const int blk = blockIdx.x;
  const int tid = threadIdx.x;
  if (blk < 256) {
    int idx = blk * 256 + tid;
    int k = idx >> 9, c = idx & 511;
    float wh = W2a[(size_t)(HIDC + k) * OUTC2 + (c & 255)];
    float w = (c < OUTC2) ? (W2a[(size_t)k * OUTC2 + c] - wh) : wh;
    unsigned short hi = bf16_rn(w);
    float fh = __uint_as_float(((unsigned int)hi) << 16);
    unsigned short lo = bf16_rn(w - fh);
    const int nt = c >> 4, ct = c & 15;
    const int s = k >> 5, kg = (k >> 3) & 3, e = k & 7;
    const size_t fidx = ((size_t)(s * 32 + nt) * 64 + (kg * 16 + ct)) * 8 + e;
    WcFhi[fidx] = hi;
    WcFlo[fidx] = lo;
  } else if (blk < 384) {
    if (tid < HIDC) {
      const int c = blk - 256;
      const int k = tid;
      float w = W1b[(size_t)k * HIDC + c];
      unsigned short hi = bf16_rn(w);
      float fh = __uint_as_float(((unsigned int)hi) << 16);
      unsigned short lo = bf16_rn(w - fh);
      const int nt = c >> 4, ct = c & 15;
      const int s = k >> 5, kg = (k >> 3) & 3, e = k & 7;
      const size_t idx = ((size_t)(s * 8 + nt) * 64 + (kg * 16 + ct)) * 8 + e;
      W1bFhi[idx] = hi;
      W1bFlo[idx] = lo;
    }
  } else {
    const int c = blk - 384;
    const int k = tid;
    float w = W2b[(size_t)k * OUTC2 + c];
    unsigned short hi = bf16_rn(w);
    float fh = __uint_as_float(((unsigned int)hi) << 16);
    unsigned short lo = bf16_rn(w - fh);
    const int nt = c >> 4, ct = c & 15;
    const int s  = k >> 5, kg = (k >> 3) & 3, e = k & 7;
    const size_t idx = ((size_t)(s * 16 + nt) * 64 + (kg * 16 + ct)) * 8 + e;
    W2Fhi[idx] = hi;
    W2Flo[idx] = lo;
  }
}

// ---------------------------------------------------------------- KNN1 (C=3, K=16)
// Wave = 2 queries; lane processes 8 consecutive j per step (128B contiguous),
// Batcher sort8 + guarded bitonic top-8 update per query. Exact set (unique
// keys -> order-free). Then per-lane exact fp32 rescore + 16-pop heads-merge.
__global__ __launch_bounds__(256) void knn3_kernel(const float4* __restrict__ X4,
                                                   int* __restrict__ idx_out) {
  const int tid  = threadIdx.x;
  const int lane = tid & 63;
  const int wv   = __builtin_amdgcn_readfirstlane(tid >> 6);
  const int qA   = blockIdx.x * 8 + wv * 2;
  const int qB   = qA + 1;

  const float4 qa = X4[qA];
  const float4 qb = X4[qB];

  unsigned kkA[KK2], kkB[KK2];
  #pragma unroll
  for (int k = 0; k < KK2; ++k) { kkA[k] = 0xFFFFFFFFu; kkB[k] = 0xFFFFFFFFu; }

  for (int c = 0; c < NPTS / 512; ++c) {
    const int j = c * 512 + lane * 8;
    float4 p[8];
    #pragma unroll
    for (int t = 0; t < 8; ++t) p[t] = X4[j + t];

    unsigned ka[KK2], kb[KK2];
    #pragma unroll
    for (int t = 0; t < 8; ++t) {
      float dA = fmaxf(qa.w + p[t].w - 2.f * (qa.x * p[t].x + qa.y * p[t].y + qa.z * p[t].z), 0.f);
      float dB = fmaxf(qb.w + p[t].w - 2.f * (qb.x * p[t].x + qb.y * p[t].y + qb.z * p[t].z), 0.f);
      ka[t] = (__float_as_uint(dA) & 0xFFFFE000u) | (unsigned)(j + t);
      kb[t] = (__float_as_uint(dB) & 0xFFFFE000u) | (unsigned)(j + t);
      if (j + t == qA) ka[t] = 0xFFFFFFFFu;
      if (j + t == qB) kb[t] = 0xFFFFFFFFu;
    }
    topk8_batch8(kkA, ka);
    topk8_batch8(kkB, kb);
  }

  // exact fp32 rescore of kept candidates, per query
  float kfA[KK2], kfB[KK2]; int kjA[KK2], kjB[KK2];
  #pragma unroll
  for (int k = 0; k < KK2; ++k) {
    kfA[k] = INFINITY; kjA[k] = 0x7fffffff;
    kfB[k] = INFINITY; kjB[k] = 0x7fffffff;
  }
  #pragma unroll
  for (int k = 0; k < KK2; ++k) {
    int j = (int)(kkA[k] & 0x1FFFu);
    float4 pj = X4[j];
    float d = qa.w + pj.w - 2.f * (qa.x * pj.x + qa.y * pj.y + qa.z * pj.z);
    if (kkA[k] == 0xFFFFFFFFu) { d = INFINITY; j = 0x7fffffff; }
    ins_lex<KK2>(kfA, kjA, d, j);
  }
  #pragma unroll
  for (int k = 0; k < KK2; ++k) {
    int j = (int)(kkB[k] & 0x1FFFu);
    float4 pj = X4[j];
    float d = qb.w + pj.w - 2.f * (qb.x * pj.x + qb.y * pj.y + qb.z * pj.z);
    if (kkB[k] == 0xFFFFFFFFu) { d = INFINITY; j = 0x7fffffff; }
    ins_lex<KK2>(kfB, kjB, d, j);
  }

  // heads-merge: 16 pops of wave-wide lex-argmin; query A then query B
  #pragma unroll
  for (int k = 0; k < KK1; ++k) {
    float mf = kfA[0]; int mj = kjA[0];
    #pragma unroll
    for (int m = 1; m <= 32; m <<= 1) {
      float of = __shfl_xor(mf, m, 64);
      int   oj = __shfl_xor(mj, m, 64);
      bool g = (of < mf) || (of == mf && oj < mj);
      mf = g ? of : mf; mj = g ? oj : mj;
    }
    const bool won = (kfA[0] == mf) && (kjA[0] == mj);
    if (won) {
      idx_out[(size_t)qA * KK1 + k] = mj;
      #pragma unroll
      for (int p = 0; p < KK2 - 1; ++p) { kfA[p] = kfA[p + 1]; kjA[p] = kjA[p + 1]; }
      kfA[KK2 - 1] = INFINITY; kjA[KK2 - 1] = 0x7fffffff;
    }
  }
  #pragma unroll
  for (int k = 0; k < KK1; ++k) {
    float mf = kfB[0]; int mj = kjB[0];
    #pragma unroll
    for (int m = 1; m <= 32; m <<= 1) {
      float of = __shfl_xor(mf, m, 64);
      int   oj = __shfl_xor(mj, m, 64);
      bool g = (of < mf) || (of == mf && oj < mj);
      mf = g ? of : mf; mj = g ? oj : mj;
    }
    const bool won = (kfB[0] == mf) && (kjB[0] == mj);
    if (won) {
      idx_out[(size_t)qB * KK1 + k] = mj;
      #pragma unroll
      for (int p = 0; p < KK2 - 1; ++p) { kfB[p] = kfB[p + 1]; kjB[p] = kjB[p + 1]; }
      kfB[KK2 - 1] = INFINITY; kjB[KK2 - 1] = 0x7fffffff;
    }
  }
}

// ---------------------------------------------------------------- EdgeConv 1 — MFMA stage-2 (R16-validated)
__global__ __launch_bounds__(512) void edgeconv1_kernel(
    const float* __restrict__ X, const int* __restrict__ knn,
    const float* __restrict__ W1, const float* __restrict__ b1,
    const unsigned short* __restrict__ W1bFhi, const unsigned short* __restrict__ W1bFlo,
    const float* __restrict__ b2,
    float* __restrict__ H, unsigned short* __restrict__ Hhi,
    unsigned short* __restrict__ Hlo, float* __restrict__ SQ2) {
  __shared__ __align__(16) unsigned short Ghi[128 * HIDC];
  __shared__ __align__(16) unsigned short Glo[128 * HIDC];
  __shared__ __align__(16) unsigned short Bs[2][2][4096];
  __shared__ float xjs[8][KK1][3];
  __shared__ float xis[8][3];
  const int tid  = threadIdx.x;
  const int lane = tid & 63;
  const int wv   = __builtin_amdgcn_readfirstlane(tid >> 6);
  const int p    = blockIdx.x * 8 + wv;

  if (lane < KK1) {
    int j = knn[p * KK1 + lane];
    xjs[wv][lane][0] = X[3 * j]; xjs[wv][lane][1] = X[3 * j + 1]; xjs[wv][lane][2] = X[3 * j + 2];
  } else if (lane < KK1 + 3) {
    xis[wv][lane - KK1] = X[3 * p + lane - KK1];
  }
  __syncthreads();

  {
    const int ch0 = lane * 2;
    float2 w1r[6];
    #pragma unroll
    for (int c = 0; c < 6; ++c)
      w1r[c] = make_float2(W1[c * HIDC + ch0], W1[c * HIDC + ch0 + 1]);
    const float2 b1v = make_float2(b1[ch0], b1[ch0 + 1]);
    const float xi0 = xis[wv][0], xi1 = xis[wv][1], xi2 = xis[wv][2];
    const float base0 = b1v.x + xi0 * w1r[0].x + xi1 * w1r[1].x + xi2 * w1r[2].x;
    const float base1 = b1v.y + xi0 * w1r[0].y + xi1 * w1r[1].y + xi2 * w1r[2].y;
    #pragma unroll
    for (int e = 0; e < KK1; ++e) {
      float dx = xjs[wv][e][0] - xi0, dy = xjs[wv][e][1] - xi1, dz = xjs[wv][e][2] - xi2;
      float v0 = fmaxf(base0 + dx * w1r[3].x + dy * w1r[4].x + dz * w1r[5].x, 0.f);
      float v1 = fmaxf(base1 + dx * w1r[3].y + dy * w1r[4].y + dz * w1r[5].y, 0.f);
      unsigned short h0 = bf16_rn(v0), h1s = bf16_rn(v1);
      unsigned short l0 = bf16_rn(v0 - __uint_as_float(((unsigned)h0) << 16));
      unsigned short l1 = bf16_rn(v1 - __uint_as_float(((unsigned)h1s) << 16));
      const int r   = wv * 16 + e;
      const int off = r * 256 + (((ch0 >> 3) ^ (r & 7)) << 4) + ((ch0 & 7) << 1);
      *(ushort2*)((char*)Ghi + off) = make_ushort2(h0, h1s);
      *(ushort2*)((char*)Glo + off) = make_ushort2(l0, l1);
    }
  }

  auto stageB = [&](int buf, int s) {
    const size_t go = (size_t)s * 4096 + (size_t)wv * 512 + (size_t)lane * 8;
    async_ld16((char*)&Bs[buf][0][0] + wv * 1024, W1bFhi + go);
    async_ld16((char*)&Bs[buf][1][0] + wv * 1024, W1bFlo + go);
  };

  stageB(0, 0);
  asm volatile("s_waitcnt vmcnt(0)" ::: "memory");
  __syncthreads();

  const int col = lane & 15;
  const int kg  = lane >> 4;
  const int ar  = wv * 16 + col;
  const int abase = ar * 256;

  f32x4 acc[8];
  #pragma unroll
  for (int n = 0; n < 8; ++n) acc[n] = (f32x4){0.f, 0.f, 0.f, 0.f};

  for (int s = 0; s < 4; ++s) {
    const int cur = s & 1;
    if (s + 1 < 4) stageB(cur ^ 1, s + 1);
    const int asl = (((s * 4 + kg) ^ (ar & 7)) << 4);
    short8 ghi = *(const short8*)((const char*)Ghi + abase + asl);
    short8 glo = *(const short8*)((const char*)Glo + abase + asl);
    #pragma unroll
    for (int n = 0; n < 8; ++n) {
      const int bo = (n * 64 + lane) * 16;
      short8 bhi = *(const short8*)((const char*)&Bs[cur][0][0] + bo);
      short8 blo = *(const short8*)((const char*)&Bs[cur][1][0] + bo);
      acc[n] = mfma16(ghi, bhi, acc[n]);
      acc[n] = mfma16(ghi, blo, acc[n]);
      acc[n] = mfma16(glo, bhi, acc[n]);
    }
    asm volatile("s_waitcnt vmcnt(0)" ::: "memory");
    __syncthreads();
  }

  float sq = 0.f;
  float hv[8];
  #pragma unroll
  for (int n = 0; n < 8; ++n) {
    float m = fmaxf(fmaxf(acc[n][0], acc[n][1]), fmaxf(acc[n][2], acc[n][3]));
    m = fmaxf(m, __shfl_xor(m, 16, 64));
    m = fmaxf(m, __shfl_xor(m, 32, 64));
    m += b2[n * 16 + col];
    hv[n] = m;
    sq += m * m;
  }
  if (kg == 0) {
    #pragma unroll
    for (int n = 0; n < 8; ++n) {
      const int ch = n * 16 + col;
      H[(size_t)p * HIDC + ch] = hv[n];
      unsigned short hb = bf16_rn(hv[n]);
      float fh = __uint_as_float(((unsigned)hb) << 16);
      Hhi[(size_t)p * HIDC + ch] = hb;
      Hlo[(size_t)p * HIDC + ch] = bf16_rn(hv[n] - fh);
    }
  }
  #pragma unroll
  for (int m2 = 1; m2 <= 8; m2 <<= 1) sq += __shfl_xor(sq, m2, 64);
  if (lane == 0) SQ2[p] = sq;
}

// ---------------------------------------------------------------- PQ = H @ Wc via MFMA (R16-validated)
__global__ __launch_bounds__(512) void gemm_pq_kernel(
    const unsigned short* __restrict__ Hhi, const unsigned short* __restrict__ Hlo,
    const unsigned short* __restrict__ WcFhi, const unsigned short* __restrict__ WcFlo,
    const float* __restrict__ b1, float* __restrict__ PQ) {
  __shared__ __align__(16) unsigned short Ahi[64 * HIDC];
  __shared__ __align__(16) unsigned short Alo[64 * HIDC];
  __shared__ __align__(16) unsigned short Bsl[2][2][8192];
  const int tid  = threadIdx.x;
  const int lane = tid & 63;
  const int wv   = __builtin_amdgcn_readfirstlane(tid >> 6);
  const int mb   = blockIdx.x >> 1;
  const int ns   = blockIdx.x & 1;
  const int r0   = mb * 64;

  #pragma unroll
  for (int i = 0; i < 2; ++i) {
    const int srow = wv * 8 + i * 4 + (lane >> 4);
    const int sslt = (lane & 15) ^ (srow & 7);
    const size_t go = (size_t)(r0 + srow) * HIDC + sslt * 8;
    async_ld16((char*)Ahi + (wv * 8 + i * 4) * 256, Hhi + go);
    async_ld16((char*)Alo + (wv * 8 + i * 4) * 256, Hlo + go);
  }
  auto stageB = [&](int buf, int s) {
    #pragma unroll
    for (int i = 0; i < 2; ++i) {
      const size_t go = (size_t)(s * 32 + ns * 16) * 512 + (size_t)wv * 1024 + i * 512 + lane * 8;
      async_ld16((char*)&Bsl[buf][0][0] + wv * 2048 + i * 1024, WcFhi + go);
      async_ld16((char*)&Bsl[buf][1][0] + wv * 2048 + i * 1024, WcFlo + go);
    }
  };
  stageB(0, 0);
  asm volatile("s_waitcnt vmcnt(0)" ::: "memory");
  __syncthreads();

  const int col = lane & 15;
  const int kg  = lane >> 4;
  const int mt  = wv & 3;
  const int nh  = wv >> 2;
  const int ar  = mt * 16 + col;
  const int abase = ar * 256;

  f32x4 acc[8];
  #pragma unroll
  for (int n = 0; n < 8; ++n) acc[n] = (f32x4){0.f, 0.f, 0.f, 0.f};

  for (int s = 0; s < 4; ++s) {
    const int cur = s & 1;
    if (s + 1 < 4) stageB(cur ^ 1, s + 1);
    const int asl = (((s * 4 + kg) ^ (ar & 7)) << 4);
    short8 ahi8 = *(const short8*)((const char*)Ahi + abase + asl);
    short8 alo8 = *(const short8*)((const char*)Alo + abase + asl);
    #pragma unroll
    for (int n = 0; n < 8; ++n) {
      const int ntl = nh * 8 + n;
      const int bo = (ntl * 64 + lane) * 16;
      short8 bhi = *(const short8*)((const char*)&Bsl[cur][0][0] + bo);
      short8 blo = *(const short8*)((const char*)&Bsl[cur][1][0] + bo);
      acc[n] = mfma16(ahi8, bhi, acc[n]);
      acc[n] = mfma16(ahi8, blo, acc[n]);
      acc[n] = mfma16(alo8, bhi, acc[n]);
    }
    asm volatile("s_waitcnt vmcnt(0)" ::: "memory");
    __syncthreads();
  }

  #pragma unroll
  for (int n = 0; n < 8; ++n) {
    const int cg = ns * 256 + (nh * 8 + n) * 16 + col;
    const float bb = (ns == 0) ? b1[cg] : 0.f;
    #pragma unroll
    for (int r = 0; r < 4; ++r) {
      const int row = r0 + mt * 16 + kg * 4 + r;
      PQ[(size_t)row * PQC + cg] = acc[n][r] + bb;
    }
  }
}

// ---------------------------------------------------------------- KNN2 filter (32-row chunks, 2 tiles/barrier)
constexpr int JSPLIT = 16;
constexpr int JPB2   = NPTS / JSPLIT;   // 512 rows per split
constexpr int NCH2   = JPB2 / 32;       // 16 chunks of 32 rows
constexpr int CPQ    = JSPLIT * KK2;    // 128 keys per query

__global__ __launch_bounds__(256) void knn128_filter_kernel(
    const unsigned short* __restrict__ Hhi, const unsigned short* __restrict__ Hlo,
    const float* __restrict__ SQ, unsigned* __restrict__ pk2) {
  __shared__ __align__(16) unsigned short As[2][2][32 * HIDC];   // 2x2x8KB = 32 KB
  const int tid  = threadIdx.x;
  const int lane = tid & 63;
  const int wv   = __builtin_amdgcn_readfirstlane(tid >> 6);
  const int qb   = blockIdx.x >> 4;
  const int js   = blockIdx.x & 15;
  const int col  = lane & 15;
  const int kg   = lane >> 4;
  const int qg   = qb * 64 + wv * 16 + col;

  short8 qhi[4], qlo[4];
  #pragma unroll
  for (int s = 0; s < 4; ++s) {
    const size_t o = (size_t)qg * HIDC + s * 32 + kg * 8;
    qhi[s] = *reinterpret_cast<const short8*>(Hhi + o);
    qlo[s] = *reinterpret_cast<const short8*>(Hlo + o);
  }
  const float sqq = SQ[qg];

  unsigned kk[KK2];
  #pragma unroll
  for (int k = 0; k < KK2; ++k) kk[k] = 0xFFFFFFFFu;

  const int jbase = js * JPB2;

  // wave stages 8 rows per chunk (two 4-row groups), per-lane swizzled source
  auto stage = [&](int buf, int ch) {
    #pragma unroll
    for (int i = 0; i < 2; ++i) {
      const int srow = 8 * wv + i * 4 + (lane >> 4);
      const int sslt = (lane & 15) ^ (srow & 7);
      const size_t gofs = (size_t)(jbase + ch * 32 + srow) * HIDC + sslt * 8;
      async_ld16((char*)&As[buf][0][0] + (8 * wv + i * 4) * 256, Hhi + gofs);
      async_ld16((char*)&As[buf][1][0] + (8 * wv + i * 4) * 256, Hlo + gofs);
    }
  };

  stage(0, 0);
  asm volatile("s_waitcnt vmcnt(0)" ::: "memory");
  __syncthreads();

  for (int ch = 0; ch < NCH2; ++ch) {
    const int cur = ch & 1;
    if (ch + 1 < NCH2) stage(cur ^ 1, ch + 1);

    #pragma unroll
    for (int t = 0; t < 2; ++t) {
      const int jb = jbase + ch * 32 + t * 16;
      short8 ahi[4], alo[4];
      const int rowb = (t * 16 + col) * 256;
      #pragma unroll
      for (int s = 0; s < 4; ++s) {
        const int sl = ((s * 4 + kg) ^ (col & 7)) * 16;
        ahi[s] = *(const short8*)((const char*)&As[cur][0][0] + rowb + sl);
        alo[s] = *(const short8*)((const char*)&As[cur][1][0] + rowb + sl);
      }
      f32x4 sqjv = *reinterpret_cast<const f32x4*>(SQ + jb + kg * 4);

      f32x4 acc = {0.f, 0.f, 0.f, 0.f};
      #pragma unroll
      for (int s = 0; s < 4; ++s) {
        acc = mfma16(ahi[s], qhi[s], acc);
        acc = mfma16(ahi[s], qlo[s], acc);
        acc = mfma16(alo[s], qhi[s], acc);
      }
      unsigned kb[4];
      #pragma unroll
      for (int r = 0; r < 4; ++r) {
        const int jg = jb + kg * 4 + r;
        float d = fmaxf(sqq + sqjv[r] - 2.f * acc[r], 0.f);
        kb[r] = (__float_as_uint(d) & 0xFFFFE000u) | (unsigned)jg;
        if (jg == qg) kb[r] = 0xFFFFFFFFu;
      }
      topk8_batch4(kk, kb[0], kb[1], kb[2], kb[3]);
    }
    asm volatile("s_waitcnt vmcnt(0)" ::: "memory");
    __syncthreads();
  }

  // merge 4 kgroup lists (sorted) -> top-8 of split
  #pragma unroll
  for (int dlt = 16; dlt <= 32; dlt <<= 1) {
    unsigned ok[KK2];
    #pragma unroll
    for (int k = 0; k < KK2; ++k) ok[k] = __shfl_xor((int)kk[k], dlt, 64);
    topk8_merge_sorted(kk, ok);
  }
  if (lane < 16) {
    const size_t base = (size_t)qg * CPQ + js * KK2;
    #pragma unroll
    for (int k = 0; k < KK2; ++k) pk2[base + k] = kk[k];
  }
}

// ---------------------------------------------------------------- rescore (unchanged from R15)
__global__ __launch_bounds__(256) void knn_rescore_kernel(
    const float* __restrict__ H, const float* __restrict__ SQ,
    const unsigned* __restrict__ pk2, int* __restrict__ idx_out) {
  __shared__ float qrow[16][HIDC + 4];
  const int tid  = threadIdx.x;
  const int lane = tid & 63;
  const int wv   = tid >> 6;
  const int g    = lane >> 4;
  const int sl   = lane & 15;
  const int q0   = blockIdx.x * 16;
  const int qloc = wv * 4 + g;
  const int q    = q0 + qloc;

  for (int u = tid; u < 16 * 32; u += 256) {
    int r = u >> 5, c4 = u & 31;
    *(f32x4*)&qrow[r][c4 * 4] = *(const f32x4*)&H[(size_t)(q0 + r) * HIDC + c4 * 4];
  }
  __syncthreads();

  unsigned kreg[KK2];
  {
    const unsigned* src = pk2 + (size_t)q * CPQ + sl * KK2;
    uint4 a = *(const uint4*)(src);
    uint4 b = *(const uint4*)(src + 4);
    kreg[0] = a.x; kreg[1] = a.y; kreg[2] = a.z; kreg[3] = a.w;
    kreg[4] = b.x; kreg[5] = b.y; kreg[6] = b.z; kreg[7] = b.w;
  }

  unsigned ckey = 0xFFFFFFFFu;
  #pragma unroll
  for (int t = 0; t < 16; ++t) {
    unsigned m = kreg[0];
    #pragma unroll
    for (int mm = 1; mm <= 8; mm <<= 1) {
      unsigned o = (unsigned)__shfl_xor((int)m, mm, 64);
      m = o < m ? o : m;
    }
    if (t == sl) ckey = m;
    const bool won = (kreg[0] == m);
    if (won) {
      #pragma unroll
      for (int p = 0; p < KK2 - 1; ++p) kreg[p] = kreg[p + 1];
      kreg[KK2 - 1] = 0xFFFFFFFFu;
    }
  }
  const int ci = (int)(ckey & 0x1FFFu);

  const float* crow = H + (size_t)ci * HIDC;
  float dot = 0.f;
  #pragma unroll 8
  for (int c4 = 0; c4 < HIDC / 4; ++c4) {
    f32x4 qv = *(const f32x4*)&qrow[qloc][c4 * 4];
    f32x4 cv = *(const f32x4*)(crow + c4 * 4);
    dot += qv[0] * cv[0] + qv[1] * cv[1] + qv[2] * cv[2] + qv[3] * cv[3];
  }
  float d = SQ[q] + SQ[ci] - 2.f * dot;

  float kf[KK2]; int ki[KK2];
  kf[0] = d; ki[0] = ci;
  #pragma unroll
  for (int k = 1; k < KK2; ++k) { kf[k] = INFINITY; ki[k] = 0x7fffffff; }
  #pragma unroll
  for (int dlt = 1; dlt <= 8; dlt <<= 1) {
    float of[KK2]; int oi[KK2];
    #pragma unroll
    for (int k = 0; k < KK2; ++k) { of[k] = __shfl_xor(kf[k], dlt, 64); oi[k] = __shfl_xor(ki[k], dlt, 64); }
    #pragma unroll
    for (int k = 0; k < KK2; ++k) ins_lex<KK2>(kf, ki, of[k], oi[k]);
  }
  if (sl == 0) {
    #pragma unroll
    for (int k = 0; k < KK2; ++k) idx_out[(size_t)q * KK2 + k] = ki[k];
  }
}

// ---------------------------------------------------------------- EdgeConv 2 — MFMA, LDS-staged B (R14-validated)
__global__ __launch_bounds__(512) void edgeconv2_kernel(
    const float* __restrict__ PQ, const int* __restrict__ knn,
    const unsigned short* __restrict__ W2Fhi, const unsigned short* __restrict__ W2Flo,
    const float* __restrict__ b2, float* __restrict__ Out) {
  __shared__ __align__(16) unsigned short Ghi[64 * OUTC2];
  __shared__ __align__(16) unsigned short Glo[64 * OUTC2];
  __shared__ __align__(16) unsigned short Bs[2][2][8192];
  const int tid  = threadIdx.x;
  const int lane = tid & 63;
  const int wv   = __builtin_amdgcn_readfirstlane(tid >> 6);
  const int p_base = blockIdx.x * 8;

  {
    const int p   = p_base + wv;
    const int ch0 = lane * 4;
    f32x4 pv = *(const f32x4*)&PQ[(size_t)p * PQC + ch0];
    #pragma unroll
    for (int e = 0; e < KK2; ++e) {
      const int j = knn[p * KK2 + e];
      f32x4 qv = *(const f32x4*)&PQ[(size_t)j * PQC + OUTC2 + ch0];
      unsigned short hb[4], lb[4];
      #pragma unroll
      for (int c = 0; c < 4; ++c) {
        float g = fmaxf(pv[c] + qv[c], 0.f);
        hb[c] = bf16_rn(g);
        float fh = __uint_as_float(((unsigned int)hb[c]) << 16);
        lb[c] = bf16_rn(g - fh);
      }
      const int r   = wv * 8 + e;
      const int off = r * 512 + (((ch0 >> 3) ^ (r & 7)) << 4) + ((ch0 & 7) << 1);
      *(ushort4*)((char*)Ghi + off) = make_ushort4(hb[0], hb[1], hb[2], hb[3]);
      *(ushort4*)((char*)Glo + off) = make_ushort4(lb[0], lb[1], lb[2], lb[3]);
    }
  }

  auto stageB = [&](int buf, int s) {
    #pragma unroll
    for (int i = 0; i < 2; ++i) {
      const size_t go = (size_t)s * 8192 + (size_t)(wv * 2 + i) * 512 + (size_t)lane * 8;
      async_ld16((char*)&Bs[buf][0][0] + (wv * 2 + i) * 1024, W2Fhi + go);
      async_ld16((char*)&Bs[buf][1][0] + (wv * 2 + i) * 1024, W2Flo + go);
    }
  };

  stageB(0, 0);
  asm volatile("s_waitcnt vmcnt(0)" ::: "memory");
  __syncthreads();

  const int col = lane & 15;
  const int kg  = lane >> 4;
  const int mt  = wv & 3;
  const int nh  = wv >> 2;
  const int ar  = mt * 16 + col;
  const int abase = ar * 512;

  f32x4 acc[8];
  #pragma unroll
  for (int n = 0; n < 8; ++n) acc[n] = (f32x4){0.f, 0.f, 0.f, 0.f};

  for (int s = 0; s < 8; ++s) {
    const int cur = s & 1;
    if (s + 1 < 8) stageB(cur ^ 1, s + 1);

    const int asl = (((s * 4 + kg) ^ (ar & 7)) << 4);
    short8 ghi = *(const short8*)((const char*)Ghi + abase + asl);
    short8 glo = *(const short8*)((const char*)Glo + abase + asl);
    #pragma unroll
    for (int n = 0; n < 8; ++n) {
      const int nt = nh * 8 + n;
      const int bo = (nt * 64 + lane) * 16;
      short8 bhi = *(const short8*)((const char*)&Bs[cur][0][0] + bo);
      short8 blo = *(const short8*)((const char*)&Bs[cur][1][0] + bo);
      acc[n] = mfma16(ghi, bhi, acc[n]);
      acc[n] = mfma16(ghi, blo, acc[n]);
      acc[n] = mfma16(glo, bhi, acc[n]);
    }
    asm volatile("s_waitcnt vmcnt(0)" ::: "memory");
    __syncthreads();
  }

  const int pt = p_base + mt * 2 + (kg >> 1);
  #pragma unroll
  for (int n = 0; n < 8; ++n) {
    float m = fmaxf(fmaxf(acc[n][0], acc[n][1]), fmaxf(acc[n][2], acc[n][3]));
    m = fmaxf(m, __shfl_xor(m, 16, 64));
    if ((kg & 1) == 0) {
      const int ncol = nh * 128 + n * 16 + col;
      Out[(size_t)pt * OUTC2 + ncol] = m + b2[ncol];
    }
  }
}

// ---------------------------------------------------------------- launch
extern "C" void kernel_launch(void* const* d_in, const int* in_sizes, int n_in,
                              void* d_out, int out_size, void* d_ws, size_t ws_size,
                              hipStream_t stream) {
  const float* x   = (const float*)d_in[0];
  const float* W1a = (const float*)d_in[1];
  const float* b1a = (const float*)d_in[2];
  const float* W1b = (const float*)d_in[3];
  const float* b1b = (const float*)d_in[4];
  const float* W2a = (const float*)d_in[5];
  const float* b2a = (const float*)d_in[6];
  const float* W2b = (const float*)d_in[7];
  const float* b2b = (const float*)d_in[8];
  float* out = (float*)d_out;

  float* h    = (float*)d_ws;                       // 4 MB
  float* sq2  = h + (size_t)NPTS * HIDC;
  int*   idx1 = (int*)(sq2 + NPTS);
  int*   idx2 = idx1 + (size_t)NPTS * KK1;
  unsigned short* Hhi = (unsigned short*)(idx2 + (size_t)NPTS * KK2);  // 2 MB
  unsigned short* Hlo = Hhi + (size_t)NPTS * HIDC;                     // 2 MB
  unsigned* pk2 = (unsigned*)(Hlo + (size_t)NPTS * HIDC);              // 4 MB
  float* PQ   = (float*)(pk2 + (size_t)NPTS * CPQ); // 16 MB
  unsigned short* W2Fhi = (unsigned short*)(PQ + (size_t)NPTS * PQC);  // 128 KB
  unsigned short* W2Flo = W2Fhi + (size_t)OUTC2 * OUTC2;               // 128 KB
  unsigned short* WcFhi = W2Flo + (size_t)OUTC2 * OUTC2;               // 128 KB
  unsigned short* WcFlo = WcFhi + (size_t)HIDC * PQC;                  // 128 KB
  unsigned short* W1bFhi = WcFlo + (size_t)HIDC * PQC;                 // 32 KB
  unsigned short* W1bFlo = W1bFhi + (size_t)HIDC * HIDC;               // 32 KB
  // x4 aliases h's first 128KB: knn3 finishes before edgeconv1 writes h.
  float4* x4 = (float4*)h;

  pack_x_kernel<<<(NPTS + 255) / 256, 256, 0, stream>>>(x, x4);
  prep_weights_kernel<<<640, 256, 0, stream>>>(W2a, W1b, W2b,
                                               WcFhi, WcFlo, W1bFhi, W1bFlo,
                                               W2Fhi, W2Flo);
  knn3_kernel<<<NPTS / 8, 256, 0, stream>>>(x4, idx1);
  edgeconv1_kernel<<<NPTS / 8, 512, 0, stream>>>(x, idx1, W1a, b1a,
                                                 W1bFhi, W1bFlo, b1b,
                                                 h, Hhi, Hlo, sq2);
  gemm_pq_kernel<<<(NPTS / 64) * 2, 512, 0, stream>>>(Hhi, Hlo, WcFhi, WcFlo, b2a, PQ);
  knn128_filter_kernel<<<(NPTS / 64) * JSPLIT, 256, 0, stream>>>(Hhi, Hlo, sq2, pk2);
  knn_rescore_kernel<<<NPTS / 16, 256, 0, stream>>>(h, sq2, pk2, idx2);
  edgeconv2_kernel<<<NPTS / 8, 512, 0, stream>>>(PQ, idx2, W2Fhi, W2Flo, b2b, out);
}

// Round 19
// 264.094 us; speedup vs baseline: 1.0807x; 1.0807x over previous
//
#include <hip/hip_runtime.h>
#include <math.h>

constexpr int NPTS  = 8192;
constexpr int HIDC  = 128;
constexpr int OUTC2 = 256;
constexpr int PQC   = 512;
constexpr int KK1   = 16;
constexpr int KK2   = 8;

typedef __attribute__((ext_vector_type(8))) short short8;
typedef __attribute__((ext_vector_type(4))) float f32x4;

__device__ __forceinline__ f32x4 mfma16(short8 a, short8 b, f32x4 c) {
  return __builtin_amdgcn_mfma_f32_16x16x32_bf16(a, b, c, 0, 0, 0);
}

__device__ __forceinline__ void async_ld16(void* lds, const void* g) {
  __builtin_amdgcn_global_load_lds(
      (const __attribute__((address_space(1))) unsigned int*)g,
      (__attribute__((address_space(3))) unsigned int*)lds, 16, 0, 0);
}

#define CEU(a, b) { unsigned _t = (a) < (b) ? (a) : (b); (b) = (a) < (b) ? (b) : (a); (a) = _t; }

// guarded bitonic halver + 12-CE merge: kk asc, b asc -> kk = smallest-8 asc.
__device__ __forceinline__ void topk8_merge_sorted(unsigned (&kk)[KK2], unsigned (&b)[KK2]) {
  if (b[0] < kk[7]) {
    kk[0] = kk[0] < b[7] ? kk[0] : b[7];
    kk[1] = kk[1] < b[6] ? kk[1] : b[6];
    kk[2] = kk[2] < b[5] ? kk[2] : b[5];
    kk[3] = kk[3] < b[4] ? kk[3] : b[4];
    kk[4] = kk[4] < b[3] ? kk[4] : b[3];
    kk[5] = kk[5] < b[2] ? kk[5] : b[2];
    kk[6] = kk[6] < b[1] ? kk[6] : b[1];
    kk[7] = kk[7] < b[0] ? kk[7] : b[0];
    CEU(kk[0], kk[4]); CEU(kk[1], kk[5]); CEU(kk[2], kk[6]); CEU(kk[3], kk[7]);
    CEU(kk[0], kk[2]); CEU(kk[1], kk[3]); CEU(kk[4], kk[6]); CEU(kk[5], kk[7]);
    CEU(kk[0], kk[1]); CEU(kk[2], kk[3]); CEU(kk[4], kk[5]); CEU(kk[6], kk[7]);
  }
}

// sort4 + guarded halver (R17-validated).
__device__ __forceinline__ void topk8_batch4(unsigned (&kk)[KK2],
                                             unsigned b0, unsigned b1,
                                             unsigned b2, unsigned b3) {
  CEU(b0, b1); CEU(b2, b3); CEU(b0, b2); CEU(b1, b3); CEU(b1, b2);
  if (b0 < kk[7]) {
    kk[4] = kk[4] < b3 ? kk[4] : b3;
    kk[5] = kk[5] < b2 ? kk[5] : b2;
    kk[6] = kk[6] < b1 ? kk[6] : b1;
    kk[7] = kk[7] < b0 ? kk[7] : b0;
    CEU(kk[0], kk[4]); CEU(kk[1], kk[5]); CEU(kk[2], kk[6]); CEU(kk[3], kk[7]);
    CEU(kk[0], kk[2]); CEU(kk[1], kk[3]); CEU(kk[4], kk[6]); CEU(kk[5], kk[7]);
    CEU(kk[0], kk[1]); CEU(kk[2], kk[3]); CEU(kk[4], kk[5]); CEU(kk[6], kk[7]);
  }
}

// lexicographic (d, idx) insert — exact fp32 merging.
template <int K>
__device__ __forceinline__ void ins_lex(float (&kf)[K], int (&ki)[K], float v, int j) {
  bool ins = (v < kf[K - 1]) || (v == kf[K - 1] && j < ki[K - 1]);
  if (ins) {
    kf[K - 1] = v; ki[K - 1] = j;
    #pragma unroll
    for (int p = K - 1; p > 0; --p) {
      float fa = kf[p - 1], fb = kf[p];
      int   ia = ki[p - 1], ib = ki[p];
      bool sw = (fb < fa) || (fb == fa && ib < ia);
      kf[p - 1] = sw ? fb : fa; ki[p - 1] = sw ? ib : ia;
      kf[p]     = sw ? fa : fb; ki[p]     = sw ? ia : ib;
    }
  }
}

__device__ __forceinline__ unsigned short bf16_rn(float x) {
  unsigned int u = __float_as_uint(x);
  unsigned int r = u + 0x7fffu + ((u >> 16) & 1u);
  return (unsigned short)(r >> 16);
}

// ---------------------------------------------------------------- pack x
__global__ void pack_x_kernel(const float* __restrict__ x, float4* __restrict__ x4) {
  int i = blockIdx.x * blockDim.x + threadIdx.x;
  if (i < NPTS) {
    float a = x[3 * i], b = x[3 * i + 1], c = x[3 * i + 2];
    x4[i] = make_float4(a, b, c, a * a + b * b + c * c);
  }
}

// ---------------------------------------------------------------- merged weight prep
__global__ void prep_weights_kernel(
    const float* __restrict__ W2a, const float* __restrict__ W1b,
    const float* __restrict__ W2b,
    unsigned short* __restrict__ WcFhi, unsigned short* __restrict__ WcFlo,
    unsigned short* __restrict__ W1bFhi, unsigned short* __restrict__ W1bFlo,
    unsigned short* __restrict__ W2Fhi, unsigned short* __restrict__ W2Flo) {
  const int blk = blockIdx.x;
  const int tid = threadIdx.x;
  if (blk < 256) {
    int idx = blk * 256 + tid;
    int k = idx >> 9, c = idx & 511;
    float wh = W2a[(size_t)(HIDC + k) * OUTC2 + (c & 255)];
    float w = (c < OUTC2) ? (W2a[(size_t)k * OUTC2 + c] - wh) : wh;
    unsigned short hi = bf16_rn(w);
    float fh = __uint_as_float(((unsigned int)hi) << 16);
    unsigned short lo = bf16_rn(w - fh);
    const int nt = c >> 4, ct = c & 15;
    const int s = k >> 5, kg = (k >> 3) & 3, e = k & 7;
    const size_t fidx = ((size_t)(s * 32 + nt) * 64 + (kg * 16 + ct)) * 8 + e;
    WcFhi[fidx] = hi;
    WcFlo[fidx] = lo;
  } else if (blk < 384) {
    if (tid < HIDC) {
      const int c = blk - 256;
      const int k = tid;
      float w = W1b[(size_t)k * HIDC + c];
      unsigned short hi = bf16_rn(w);
      float fh = __uint_as_float(((unsigned int)hi) << 16);
      unsigned short lo = bf16_rn(w - fh);
      const int nt = c >> 4, ct = c & 15;
      const int s = k >> 5, kg = (k >> 3) & 3, e = k & 7;
      const size_t idx = ((size_t)(s * 8 + nt) * 64 + (kg * 16 + ct)) * 8 + e;
      W1bFhi[idx] = hi;
      W1bFlo[idx] = lo;
    }
  } else {
    const int c = blk - 384;
    const int k = tid;
    float w = W2b[(size_t)k * OUTC2 + c];
    unsigned short hi = bf16_rn(w);
    float fh = __uint_as_float(((unsigned int)hi) << 16);
    unsigned short lo = bf16_rn(w - fh);
    const int nt = c >> 4, ct = c & 15;
    const int s  = k >> 5, kg = (k >> 3) & 3, e = k & 7;
    const size_t idx = ((size_t)(s * 16 + nt) * 64 + (kg * 16 + ct)) * 8 + e;
    W2Fhi[idx] = hi;
    W2Flo[idx] = lo;
  }
}

// ---------------------------------------------------------------- KNN1 (C=3, K=16) — R17-validated (batch4, 2 q/wave)
__global__ __launch_bounds__(256) void knn3_kernel(const float4* __restrict__ X4,
                                                   int* __restrict__ idx_out) {
  const int tid  = threadIdx.x;
  const int lane = tid & 63;
  const int wv   = __builtin_amdgcn_readfirstlane(tid >> 6);
  const int qA   = blockIdx.x * 8 + wv * 2;
  const int qB   = qA + 1;

  const float4 qa = X4[qA];
  const float4 qb = X4[qB];

  unsigned kkA[KK2], kkB[KK2];
  #pragma unroll
  for (int k = 0; k < KK2; ++k) { kkA[k] = 0xFFFFFFFFu; kkB[k] = 0xFFFFFFFFu; }

  for (int c = 0; c < NPTS / 256; ++c) {
    const int j = c * 256 + lane * 4;
    float4 p[4];
    #pragma unroll
    for (int t = 0; t < 4; ++t) p[t] = X4[j + t];

    unsigned ka[4], kb[4];
    #pragma unroll
    for (int t = 0; t < 4; ++t) {
      float dA = fmaxf(qa.w + p[t].w - 2.f * (qa.x * p[t].x + qa.y * p[t].y + qa.z * p[t].z), 0.f);
      float dB = fmaxf(qb.w + p[t].w - 2.f * (qb.x * p[t].x + qb.y * p[t].y + qb.z * p[t].z), 0.f);
      ka[t] = (__float_as_uint(dA) & 0xFFFFE000u) | (unsigned)(j + t);
      kb[t] = (__float_as_uint(dB) & 0xFFFFE000u) | (unsigned)(j + t);
      if (j + t == qA) ka[t] = 0xFFFFFFFFu;
      if (j + t == qB) kb[t] = 0xFFFFFFFFu;
    }
    topk8_batch4(kkA, ka[0], ka[1], ka[2], ka[3]);
    topk8_batch4(kkB, kb[0], kb[1], kb[2], kb[3]);
  }

  // exact fp32 rescore of kept candidates, per query
  float kfA[KK2], kfB[KK2]; int kjA[KK2], kjB[KK2];
  #pragma unroll
  for (int k = 0; k < KK2; ++k) {
    kfA[k] = INFINITY; kjA[k] = 0x7fffffff;
    kfB[k] = INFINITY; kjB[k] = 0x7fffffff;
  }
  #pragma unroll
  for (int k = 0; k < KK2; ++k) {
    int j = (int)(kkA[k] & 0x1FFFu);
    float4 pj = X4[j];
    float d = qa.w + pj.w - 2.f * (qa.x * pj.x + qa.y * pj.y + qa.z * pj.z);
    if (kkA[k] == 0xFFFFFFFFu) { d = INFINITY; j = 0x7fffffff; }
    ins_lex<KK2>(kfA, kjA, d, j);
  }
  #pragma unroll
  for (int k = 0; k < KK2; ++k) {
    int j = (int)(kkB[k] & 0x1FFFu);
    float4 pj = X4[j];
    float d = qb.w + pj.w - 2.f * (qb.x * pj.x + qb.y * pj.y + qb.z * pj.z);
    if (kkB[k] == 0xFFFFFFFFu) { d = INFINITY; j = 0x7fffffff; }
    ins_lex<KK2>(kfB, kjB, d, j);
  }

  // heads-merge: 16 pops of wave-wide lex-argmin; query A then query B
  #pragma unroll
  for (int k = 0; k < KK1; ++k) {
    float mf = kfA[0]; int mj = kjA[0];
    #pragma unroll
    for (int m = 1; m <= 32; m <<= 1) {
      float of = __shfl_xor(mf, m, 64);
      int   oj = __shfl_xor(mj, m, 64);
      bool g = (of < mf) || (of == mf && oj < mj);
      mf = g ? of : mf; mj = g ? oj : mj;
    }
    const bool won = (kfA[0] == mf) && (kjA[0] == mj);
    if (won) {
      idx_out[(size_t)qA * KK1 + k] = mj;
      #pragma unroll
      for (int p = 0; p < KK2 - 1; ++p) { kfA[p] = kfA[p + 1]; kjA[p] = kjA[p + 1]; }
      kfA[KK2 - 1] = INFINITY; kjA[KK2 - 1] = 0x7fffffff;
    }
  }
  #pragma unroll
  for (int k = 0; k < KK1; ++k) {
    float mf = kfB[0]; int mj = kjB[0];
    #pragma unroll
    for (int m = 1; m <= 32; m <<= 1) {
      float of = __shfl_xor(mf, m, 64);
      int   oj = __shfl_xor(mj, m, 64);
      bool g = (of < mf) || (of == mf && oj < mj);
      mf = g ? of : mf; mj = g ? oj : mj;
    }
    const bool won = (kfB[0] == mf) && (kjB[0] == mj);
    if (won) {
      idx_out[(size_t)qB * KK1 + k] = mj;
      #pragma unroll
      for (int p = 0; p < KK2 - 1; ++p) { kfB[p] = kfB[p + 1]; kjB[p] = kjB[p + 1]; }
      kfB[KK2 - 1] = INFINITY; kjB[KK2 - 1] = 0x7fffffff;
    }
  }
}

// ---------------------------------------------------------------- EdgeConv 1 — MFMA stage-2 (R16-validated)
__global__ __launch_bounds__(512) void edgeconv1_kernel(
    const float* __restrict__ X, const int* __restrict__ knn,
    const float* __restrict__ W1, const float* __restrict__ b1,
    const unsigned short* __restrict__ W1bFhi, const unsigned short* __restrict__ W1bFlo,
    const float* __restrict__ b2,
    float* __restrict__ H, unsigned short* __restrict__ Hhi,
    unsigned short* __restrict__ Hlo, float* __restrict__ SQ2) {
  __shared__ __align__(16) unsigned short Ghi[128 * HIDC];
  __shared__ __align__(16) unsigned short Glo[128 * HIDC];
  __shared__ __align__(16) unsigned short Bs[2][2][4096];
  __shared__ float xjs[8][KK1][3];
  __shared__ float xis[8][3];
  const int tid  = threadIdx.x;
  const int lane = tid & 63;
  const int wv   = __builtin_amdgcn_readfirstlane(tid >> 6);
  const int p    = blockIdx.x * 8 + wv;

  if (lane < KK1) {
    int j = knn[p * KK1 + lane];
    xjs[wv][lane][0] = X[3 * j]; xjs[wv][lane][1] = X[3 * j + 1]; xjs[wv][lane][2] = X[3 * j + 2];
  } else if (lane < KK1 + 3) {
    xis[wv][lane - KK1] = X[3 * p + lane - KK1];
  }
  __syncthreads();

  {
    const int ch0 = lane * 2;
    float2 w1r[6];
    #pragma unroll
    for (int c = 0; c < 6; ++c)
      w1r[c] = make_float2(W1[c * HIDC + ch0], W1[c * HIDC + ch0 + 1]);
    const float2 b1v = make_float2(b1[ch0], b1[ch0 + 1]);
    const float xi0 = xis[wv][0], xi1 = xis[wv][1], xi2 = xis[wv][2];
    const float base0 = b1v.x + xi0 * w1r[0].x + xi1 * w1r[1].x + xi2 * w1r[2].x;
    const float base1 = b1v.y + xi0 * w1r[0].y + xi1 * w1r[1].y + xi2 * w1r[2].y;
    #pragma unroll
    for (int e = 0; e < KK1; ++e) {
      float dx = xjs[wv][e][0] - xi0, dy = xjs[wv][e][1] - xi1, dz = xjs[wv][e][2] - xi2;
      float v0 = fmaxf(base0 + dx * w1r[3].x + dy * w1r[4].x + dz * w1r[5].x, 0.f);
      float v1 = fmaxf(base1 + dx * w1r[3].y + dy * w1r[4].y + dz * w1r[5].y, 0.f);
      unsigned short h0 = bf16_rn(v0), h1s = bf16_rn(v1);
      unsigned short l0 = bf16_rn(v0 - __uint_as_float(((unsigned)h0) << 16));
      unsigned short l1 = bf16_rn(v1 - __uint_as_float(((unsigned)h1s) << 16));
      const int r   = wv * 16 + e;
      const int off = r * 256 + (((ch0 >> 3) ^ (r & 7)) << 4) + ((ch0 & 7) << 1);
      *(ushort2*)((char*)Ghi + off) = make_ushort2(h0, h1s);
      *(ushort2*)((char*)Glo + off) = make_ushort2(l0, l1);
    }
  }

  auto stageB = [&](int buf, int s) {
    const size_t go = (size_t)s * 4096 + (size_t)wv * 512 + (size_t)lane * 8;
    async_ld16((char*)&Bs[buf][0][0] + wv * 1024, W1bFhi + go);
    async_ld16((char*)&Bs[buf][1][0] + wv * 1024, W1bFlo + go);
  };

  stageB(0, 0);
  asm volatile("s_waitcnt vmcnt(0)" ::: "memory");
  __syncthreads();

  const int col = lane & 15;
  const int kg  = lane >> 4;
  const int ar  = wv * 16 + col;
  const int abase = ar * 256;

  f32x4 acc[8];
  #pragma unroll
  for (int n = 0; n < 8; ++n) acc[n] = (f32x4){0.f, 0.f, 0.f, 0.f};

  for (int s = 0; s < 4; ++s) {
    const int cur = s & 1;
    if (s + 1 < 4) stageB(cur ^ 1, s + 1);
    const int asl = (((s * 4 + kg) ^ (ar & 7)) << 4);
    short8 ghi = *(const short8*)((const char*)Ghi + abase + asl);
    short8 glo = *(const short8*)((const char*)Glo + abase + asl);
    #pragma unroll
    for (int n = 0; n < 8; ++n) {
      const int bo = (n * 64 + lane) * 16;
      short8 bhi = *(const short8*)((const char*)&Bs[cur][0][0] + bo);
      short8 blo = *(const short8*)((const char*)&Bs[cur][1][0] + bo);
      acc[n] = mfma16(ghi, bhi, acc[n]);
      acc[n] = mfma16(ghi, blo, acc[n]);
      acc[n] = mfma16(glo, bhi, acc[n]);
    }
    asm volatile("s_waitcnt vmcnt(0)" ::: "memory");
    __syncthreads();
  }

  float sq = 0.f;
  float hv[8];
  #pragma unroll
  for (int n = 0; n < 8; ++n) {
    float m = fmaxf(fmaxf(acc[n][0], acc[n][1]), fmaxf(acc[n][2], acc[n][3]));
    m = fmaxf(m, __shfl_xor(m, 16, 64));
    m = fmaxf(m, __shfl_xor(m, 32, 64));
    m += b2[n * 16 + col];
    hv[n] = m;
    sq += m * m;
  }
  if (kg == 0) {
    #pragma unroll
    for (int n = 0; n < 8; ++n) {
      const int ch = n * 16 + col;
      H[(size_t)p * HIDC + ch] = hv[n];
      unsigned short hb = bf16_rn(hv[n]);
      float fh = __uint_as_float(((unsigned)hb) << 16);
      Hhi[(size_t)p * HIDC + ch] = hb;
      Hlo[(size_t)p * HIDC + ch] = bf16_rn(hv[n] - fh);
    }
  }
  #pragma unroll
  for (int m2 = 1; m2 <= 8; m2 <<= 1) sq += __shfl_xor(sq, m2, 64);
  if (lane == 0) SQ2[p] = sq;
}

// ---------------------------------------------------------------- PQ = H @ Wc via MFMA (R16-validated)
__global__ __launch_bounds__(512) void gemm_pq_kernel(
    const unsigned short* __restrict__ Hhi, const unsigned short* __restrict__ Hlo,
    const unsigned short* __restrict__ WcFhi, const unsigned short* __restrict__ WcFlo,
    const float* __restrict__ b1, float* __restrict__ PQ) {
  __shared__ __align__(16) unsigned short Ahi[64 * HIDC];
  __shared__ __align__(16) unsigned short Alo[64 * HIDC];
  __shared__ __align__(16) unsigned short Bsl[2][2][8192];
  const int tid  = threadIdx.x;
  const int lane = tid & 63;
  const int wv   = __builtin_amdgcn_readfirstlane(tid >> 6);
  const int mb   = blockIdx.x >> 1;
  const int ns   = blockIdx.x & 1;
  const int r0   = mb * 64;

  #pragma unroll
  for (int i = 0; i < 2; ++i) {
    const int srow = wv * 8 + i * 4 + (lane >> 4);
    const int sslt = (lane & 15) ^ (srow & 7);
    const size_t go = (size_t)(r0 + srow) * HIDC + sslt * 8;
    async_ld16((char*)Ahi + (wv * 8 + i * 4) * 256, Hhi + go);
    async_ld16((char*)Alo + (wv * 8 + i * 4) * 256, Hlo + go);
  }
  auto stageB = [&](int buf, int s) {
    #pragma unroll
    for (int i = 0; i < 2; ++i) {
      const size_t go = (size_t)(s * 32 + ns * 16) * 512 + (size_t)wv * 1024 + i * 512 + lane * 8;
      async_ld16((char*)&Bsl[buf][0][0] + wv * 2048 + i * 1024, WcFhi + go);
      async_ld16((char*)&Bsl[buf][1][0] + wv * 2048 + i * 1024, WcFlo + go);
    }
  };
  stageB(0, 0);
  asm volatile("s_waitcnt vmcnt(0)" ::: "memory");
  __syncthreads();

  const int col = lane & 15;
  const int kg  = lane >> 4;
  const int mt  = wv & 3;
  const int nh  = wv >> 2;
  const int ar  = mt * 16 + col;
  const int abase = ar * 256;

  f32x4 acc[8];
  #pragma unroll
  for (int n = 0; n < 8; ++n) acc[n] = (f32x4){0.f, 0.f, 0.f, 0.f};

  for (int s = 0; s < 4; ++s) {
    const int cur = s & 1;
    if (s + 1 < 4) stageB(cur ^ 1, s + 1);
    const int asl = (((s * 4 + kg) ^ (ar & 7)) << 4);
    short8 ahi8 = *(const short8*)((const char*)Ahi + abase + asl);
    short8 alo8 = *(const short8*)((const char*)Alo + abase + asl);
    #pragma unroll
    for (int n = 0; n < 8; ++n) {
      const int ntl = nh * 8 + n;
      const int bo = (ntl * 64 + lane) * 16;
      short8 bhi = *(const short8*)((const char*)&Bsl[cur][0][0] + bo);
      short8 blo = *(const short8*)((const char*)&Bsl[cur][1][0] + bo);
      acc[n] = mfma16(ahi8, bhi, acc[n]);
      acc[n] = mfma16(ahi8, blo, acc[n]);
      acc[n] = mfma16(alo8, bhi, acc[n]);
    }
    asm volatile("s_waitcnt vmcnt(0)" ::: "memory");
    __syncthreads();
  }

  #pragma unroll
  for (int n = 0; n < 8; ++n) {
    const int cg = ns * 256 + (nh * 8 + n) * 16 + col;
    const float bb = (ns == 0) ? b1[cg] : 0.f;
    #pragma unroll
    for (int r = 0; r < 4; ++r) {
      const int row = r0 + mt * 16 + kg * 4 + r;
      PQ[(size_t)row * PQC + cg] = acc[n][r] + bb;
    }
  }
}

// ---------------------------------------------------------------- KNN2 filter (32-row chunks, R18-neutral-validated)
constexpr int JSPLIT = 16;
constexpr int JPB2   = NPTS / JSPLIT;
constexpr int NCH2   = JPB2 / 32;
constexpr int CPQ    = JSPLIT * KK2;

__global__ __launch_bounds__(256) void knn128_filter_kernel(
    const unsigned short* __restrict__ Hhi, const unsigned short* __restrict__ Hlo,
    const float* __restrict__ SQ, unsigned* __restrict__ pk2) {
  __shared__ __align__(16) unsigned short As[2][2][32 * HIDC];
  const int tid  = threadIdx.x;
  const int lane = tid & 63;
  const int wv   = __builtin_amdgcn_readfirstlane(tid >> 6);
  const int qb   = blockIdx.x >> 4;
  const int js   = blockIdx.x & 15;
  const int col  = lane & 15;
  const int kg   = lane >> 4;
  const int qg   = qb * 64 + wv * 16 + col;

  short8 qhi[4], qlo[4];
  #pragma unroll
  for (int s = 0; s < 4; ++s) {
    const size_t o = (size_t)qg * HIDC + s * 32 + kg * 8;
    qhi[s] = *reinterpret_cast<const short8*>(Hhi + o);
    qlo[s] = *reinterpret_cast<const short8*>(Hlo + o);
  }
  const float sqq = SQ[qg];

  unsigned kk[KK2];
  #pragma unroll
  for (int k = 0; k < KK2; ++k) kk[k] = 0xFFFFFFFFu;

  const int jbase = js * JPB2;

  auto stage = [&](int buf, int ch) {
    #pragma unroll
    for (int i = 0; i < 2; ++i) {
      const int srow = 8 * wv + i * 4 + (lane >> 4);
      const int sslt = (lane & 15) ^ (srow & 7);
      const size_t gofs = (size_t)(jbase + ch * 32 + srow) * HIDC + sslt * 8;
      async_ld16((char*)&As[buf][0][0] + (8 * wv + i * 4) * 256, Hhi + gofs);
      async_ld16((char*)&As[buf][1][0] + (8 * wv + i * 4) * 256, Hlo + gofs);
    }
  };

  stage(0, 0);
  asm volatile("s_waitcnt vmcnt(0)" ::: "memory");
  __syncthreads();

  for (int ch = 0; ch < NCH2; ++ch) {
    const int cur = ch & 1;
    if (ch + 1 < NCH2) stage(cur ^ 1, ch + 1);

    #pragma unroll
    for (int t = 0; t < 2; ++t) {
      const int jb = jbase + ch * 32 + t * 16;
      short8 ahi[4], alo[4];
      const int rowb = (t * 16 + col) * 256;
      #pragma unroll
      for (int s = 0; s < 4; ++s) {
        const int sl = ((s * 4 + kg) ^ (col & 7)) * 16;
        ahi[s] = *(const short8*)((const char*)&As[cur][0][0] + rowb + sl);
        alo[s] = *(const short8*)((const char*)&As[cur][1][0] + rowb + sl);
      }
      f32x4 sqjv = *reinterpret_cast<const f32x4*>(SQ + jb + kg * 4);

      f32x4 acc = {0.f, 0.f, 0.f, 0.f};
      #pragma unroll
      for (int s = 0; s < 4; ++s) {
        acc = mfma16(ahi[s], qhi[s], acc);
        acc = mfma16(ahi[s], qlo[s], acc);
        acc = mfma16(alo[s], qhi[s], acc);
      }
      unsigned kb[4];
      #pragma unroll
      for (int r = 0; r < 4; ++r) {
        const int jg = jb + kg * 4 + r;
        float d = fmaxf(sqq + sqjv[r] - 2.f * acc[r], 0.f);
        kb[r] = (__float_as_uint(d) & 0xFFFFE000u) | (unsigned)jg;
        if (jg == qg) kb[r] = 0xFFFFFFFFu;
      }
      topk8_batch4(kk, kb[0], kb[1], kb[2], kb[3]);
    }
    asm volatile("s_waitcnt vmcnt(0)" ::: "memory");
    __syncthreads();
  }

  #pragma unroll
  for (int dlt = 16; dlt <= 32; dlt <<= 1) {
    unsigned ok[KK2];
    #pragma unroll
    for (int k = 0; k < KK2; ++k) ok[k] = __shfl_xor((int)kk[k], dlt, 64);
    topk8_merge_sorted(kk, ok);
  }
  if (lane < 16) {
    const size_t base = (size_t)qg * CPQ + js * KK2;
    #pragma unroll
    for (int k = 0; k < KK2; ++k) pk2[base + k] = kk[k];
  }
}

// ---------------------------------------------------------------- rescore (R15-validated)
__global__ __launch_bounds__(256) void knn_rescore_kernel(
    const float* __restrict__ H, const float* __restrict__ SQ,
    const unsigned* __restrict__ pk2, int* __restrict__ idx_out) {
  __shared__ float qrow[16][HIDC + 4];
  const int tid  = threadIdx.x;
  const int lane = tid & 63;
  const int wv   = tid >> 6;
  const int g    = lane >> 4;
  const int sl   = lane & 15;
  const int q0   = blockIdx.x * 16;
  const int qloc = wv * 4 + g;
  const int q    = q0 + qloc;

  for (int u = tid; u < 16 * 32; u += 256) {
    int r = u >> 5, c4 = u & 31;
    *(f32x4*)&qrow[r][c4 * 4] = *(const f32x4*)&H[(size_t)(q0 + r) * HIDC + c4 * 4];
  }
  __syncthreads();

  unsigned kreg[KK2];
  {
    const unsigned* src = pk2 + (size_t)q * CPQ + sl * KK2;
    uint4 a = *(const uint4*)(src);
    uint4 b = *(const uint4*)(src + 4);
    kreg[0] = a.x; kreg[1] = a.y; kreg[2] = a.z; kreg[3] = a.w;
    kreg[4] = b.x; kreg[5] = b.y; kreg[6] = b.z; kreg[7] = b.w;
  }

  unsigned ckey = 0xFFFFFFFFu;
  #pragma unroll
  for (int t = 0; t < 16; ++t) {
    unsigned m = kreg[0];
    #pragma unroll
    for (int mm = 1; mm <= 8; mm <<= 1) {
      unsigned o = (unsigned)__shfl_xor((int)m, mm, 64);
      m = o < m ? o : m;
    }
    if (t == sl) ckey = m;
    const bool won = (kreg[0] == m);
    if (won) {
      #pragma unroll
      for (int p = 0; p < KK2 - 1; ++p) kreg[p] = kreg[p + 1];
      kreg[KK2 - 1] = 0xFFFFFFFFu;
    }
  }
  const int ci = (int)(ckey & 0x1FFFu);

  const float* crow = H + (size_t)ci * HIDC;
  float dot = 0.f;
  #pragma unroll 8
  for (int c4 = 0; c4 < HIDC / 4; ++c4) {
    f32x4 qv = *(const f32x4*)&qrow[qloc][c4 * 4];
    f32x4 cv = *(const f32x4*)(crow + c4 * 4);
    dot += qv[0] * cv[0] + qv[1] * cv[1] + qv[2] * cv[2] + qv[3] * cv[3];
  }
  float d = SQ[q] + SQ[ci] - 2.f * dot;

  float kf[KK2]; int ki[KK2];
  kf[0] = d; ki[0] = ci;
  #pragma unroll
  for (int k = 1; k < KK2; ++k) { kf[k] = INFINITY; ki[k] = 0x7fffffff; }
  #pragma unroll
  for (int dlt = 1; dlt <= 8; dlt <<= 1) {
    float of[KK2]; int oi[KK2];
    #pragma unroll
    for (int k = 0; k < KK2; ++k) { of[k] = __shfl_xor(kf[k], dlt, 64); oi[k] = __shfl_xor(ki[k], dlt, 64); }
    #pragma unroll
    for (int k = 0; k < KK2; ++k) ins_lex<KK2>(kf, ki, of[k], oi[k]);
  }
  if (sl == 0) {
    #pragma unroll
    for (int k = 0; k < KK2; ++k) idx_out[(size_t)q * KK2 + k] = ki[k];
  }
}

// ---------------------------------------------------------------- EdgeConv 2 — MFMA, LDS-staged B (R14-validated)
__global__ __launch_bounds__(512) void edgeconv2_kernel(
    const float* __restrict__ PQ, const int* __restrict__ knn,
    const unsigned short* __restrict__ W2Fhi, const unsigned short* __restrict__ W2Flo,
    const float* __restrict__ b2, float* __restrict__ Out) {
  __shared__ __align__(16) unsigned short Ghi[64 * OUTC2];
  __shared__ __align__(16) unsigned short Glo[64 * OUTC2];
  __shared__ __align__(16) unsigned short Bs[2][2][8192];
  const int tid  = threadIdx.x;
  const int lane = tid & 63;
  const int wv   = __builtin_amdgcn_readfirstlane(tid >> 6);
  const int p_base = blockIdx.x * 8;

  {
    const int p   = p_base + wv;
    const int ch0 = lane * 4;
    f32x4 pv = *(const f32x4*)&PQ[(size_t)p * PQC + ch0];
    #pragma unroll
    for (int e = 0; e < KK2; ++e) {
      const int j = knn[p * KK2 + e];
      f32x4 qv = *(const f32x4*)&PQ[(size_t)j * PQC + OUTC2 + ch0];
      unsigned short hb[4], lb[4];
      #pragma unroll
      for (int c = 0; c < 4; ++c) {
        float g = fmaxf(pv[c] + qv[c], 0.f);
        hb[c] = bf16_rn(g);
        float fh = __uint_as_float(((unsigned int)hb[c]) << 16);
        lb[c] = bf16_rn(g - fh);
      }
      const int r   = wv * 8 + e;
      const int off = r * 512 + (((ch0 >> 3) ^ (r & 7)) << 4) + ((ch0 & 7) << 1);
      *(ushort4*)((char*)Ghi + off) = make_ushort4(hb[0], hb[1], hb[2], hb[3]);
      *(ushort4*)((char*)Glo + off) = make_ushort4(lb[0], lb[1], lb[2], lb[3]);
    }
  }

  auto stageB = [&](int buf, int s) {
    #pragma unroll
    for (int i = 0; i < 2; ++i) {
      const size_t go = (size_t)s * 8192 + (size_t)(wv * 2 + i) * 512 + (size_t)lane * 8;
      async_ld16((char*)&Bs[buf][0][0] + (wv * 2 + i) * 1024, W2Fhi + go);
      async_ld16((char*)&Bs[buf][1][0] + (wv * 2 + i) * 1024, W2Flo + go);
    }
  };

  stageB(0, 0);
  asm volatile("s_waitcnt vmcnt(0)" ::: "memory");
  __syncthreads();

  const int col = lane & 15;
  const int kg  = lane >> 4;
  const int mt  = wv & 3;
  const int nh  = wv >> 2;
  const int ar  = mt * 16 + col;
  const int abase = ar * 512;

  f32x4 acc[8];
  #pragma unroll
  for (int n = 0; n < 8; ++n) acc[n] = (f32x4){0.f, 0.f, 0.f, 0.f};

  for (int s = 0; s < 8; ++s) {
    const int cur = s & 1;
    if (s + 1 < 8) stageB(cur ^ 1, s + 1);

    const int asl = (((s * 4 + kg) ^ (ar & 7)) << 4);
    short8 ghi = *(const short8*)((const char*)Ghi + abase + asl);
    short8 glo = *(const short8*)((const char*)Glo + abase + asl);
    #pragma unroll
    for (int n = 0; n < 8; ++n) {
      const int nt = nh * 8 + n;
      const int bo = (nt * 64 + lane) * 16;
      short8 bhi = *(const short8*)((const char*)&Bs[cur][0][0] + bo);
      short8 blo = *(const short8*)((const char*)&Bs[cur][1][0] + bo);
      acc[n] = mfma16(ghi, bhi, acc[n]);
      acc[n] = mfma16(ghi, blo, acc[n]);
      acc[n] = mfma16(glo, bhi, acc[n]);
    }
    asm volatile("s_waitcnt vmcnt(0)" ::: "memory");
    __syncthreads();
  }

  const int pt = p_base + mt * 2 + (kg >> 1);
  #pragma unroll
  for (int n = 0; n < 8; ++n) {
    float m = fmaxf(fmaxf(acc[n][0], acc[n][1]), fmaxf(acc[n][2], acc[n][3]));
    m = fmaxf(m, __shfl_xor(m, 16, 64));
    if ((kg & 1) == 0) {
      const int ncol = nh * 128 + n * 16 + col;
      Out[(size_t)pt * OUTC2 + ncol] = m + b2[ncol];
    }
  }
}

// ---------------------------------------------------------------- launch
extern "C" void kernel_launch(void* const* d_in, const int* in_sizes, int n_in,
                              void* d_out, int out_size, void* d_ws, size_t ws_size,
                              hipStream_t stream) {
  const float* x   = (const float*)d_in[0];
  const float* W1a = (const float*)d_in[1];
  const float* b1a = (const float*)d_in[2];
  const float* W1b = (const float*)d_in[3];
  const float* b1b = (const float*)d_in[4];
  const float* W2a = (const float*)d_in[5];
  const float* b2a = (const float*)d_in[6];
  const float* W2b = (const float*)d_in[7];
  const float* b2b = (const float*)d_in[8];
  float* out = (float*)d_out;

  float* h    = (float*)d_ws;                       // 4 MB
  float* sq2  = h + (size_t)NPTS * HIDC;
  int*   idx1 = (int*)(sq2 + NPTS);
  int*   idx2 = idx1 + (size_t)NPTS * KK1;
  unsigned short* Hhi = (unsigned short*)(idx2 + (size_t)NPTS * KK2);  // 2 MB
  unsigned short* Hlo = Hhi + (size_t)NPTS * HIDC;                     // 2 MB
  unsigned* pk2 = (unsigned*)(Hlo + (size_t)NPTS * HIDC);              // 4 MB
  float* PQ   = (float*)(pk2 + (size_t)NPTS * CPQ); // 16 MB
  unsigned short* W2Fhi = (unsigned short*)(PQ + (size_t)NPTS * PQC);  // 128 KB
  unsigned short* W2Flo = W2Fhi + (size_t)OUTC2 * OUTC2;               // 128 KB
  unsigned short* WcFhi = W2Flo + (size_t)OUTC2 * OUTC2;               // 128 KB
  unsigned short* WcFlo = WcFhi + (size_t)HIDC * PQC;                  // 128 KB
  unsigned short* W1bFhi = WcFlo + (size_t)HIDC * PQC;                 // 32 KB
  unsigned short* W1bFlo = W1bFhi + (size_t)HIDC * HIDC;               // 32 KB
  // x4 aliases h's first 128KB: knn3 finishes before edgeconv1 writes h.
  float4* x4 = (float4*)h;

  pack_x_kernel<<<(NPTS + 255) / 256, 256, 0, stream>>>(x, x4);
  prep_weights_kernel<<<640, 256, 0, stream>>>(W2a, W1b, W2b,
                                               WcFhi, WcFlo, W1bFhi, W1bFlo,
                                               W2Fhi, W2Flo);
  knn3_kernel<<<NPTS / 8, 256, 0, stream>>>(x4, idx1);
  edgeconv1_kernel<<<NPTS / 8, 512, 0, stream>>>(x, idx1, W1a, b1a,
                                                 W1bFhi, W1bFlo, b1b,
                                                 h, Hhi, Hlo, sq2);
  gemm_pq_kernel<<<(NPTS / 64) * 2, 512, 0, stream>>>(Hhi, Hlo, WcFhi, WcFlo, b2a, PQ);
  knn128_filter_kernel<<<(NPTS / 64) * JSPLIT, 256, 0, stream>>>(Hhi, Hlo, sq2, pk2);
  knn_rescore_kernel<<<NPTS / 16, 256, 0, stream>>>(h, sq2, pk2, idx2);
  edgeconv2_kernel<<<NPTS / 8, 512, 0, stream>>>(PQ, idx2, W2Fhi, W2Flo, b2b, out);
}

// Round 21
// 262.690 us; speedup vs baseline: 1.0865x; 1.0053x over previous
//
#include <hip/hip_runtime.h>
#include <math.h>

constexpr int NPTS  = 8192;
constexpr int HIDC  = 128;
constexpr int OUTC2 = 256;
constexpr int PQC   = 512;
constexpr int KK1   = 16;
constexpr int KK2   = 8;

typedef __attribute__((ext_vector_type(8))) short short8;
typedef __attribute__((ext_vector_type(4))) float f32x4;

__device__ __forceinline__ f32x4 mfma16(short8 a, short8 b, f32x4 c) {
  return __builtin_amdgcn_mfma_f32_16x16x32_bf16(a, b, c, 0, 0, 0);
}

__device__ __forceinline__ void async_ld16(void* lds, const void* g) {
  __builtin_amdgcn_global_load_lds(
      (const __attribute__((address_space(1))) unsigned int*)g,
      (__attribute__((address_space(3))) unsigned int*)lds, 16, 0, 0);
}

#define CEU(a, b) { unsigned _t = (a) < (b) ? (a) : (b); (b) = (a) < (b) ? (b) : (a); (a) = _t; }

// guarded bitonic halver + 12-CE merge: kk asc, b asc -> kk = smallest-8 asc.
__device__ __forceinline__ void topk8_merge_sorted(unsigned (&kk)[KK2], unsigned (&b)[KK2]) {
  if (b[0] < kk[7]) {
    kk[0] = kk[0] < b[7] ? kk[0] : b[7];
    kk[1] = kk[1] < b[6] ? kk[1] : b[6];
    kk[2] = kk[2] < b[5] ? kk[2] : b[5];
    kk[3] = kk[3] < b[4] ? kk[3] : b[4];
    kk[4] = kk[4] < b[3] ? kk[4] : b[3];
    kk[5] = kk[5] < b[2] ? kk[5] : b[2];
    kk[6] = kk[6] < b[1] ? kk[6] : b[1];
    kk[7] = kk[7] < b[0] ? kk[7] : b[0];
    CEU(kk[0], kk[4]); CEU(kk[1], kk[5]); CEU(kk[2], kk[6]); CEU(kk[3], kk[7]);
    CEU(kk[0], kk[2]); CEU(kk[1], kk[3]); CEU(kk[4], kk[6]); CEU(kk[5], kk[7]);
    CEU(kk[0], kk[1]); CEU(kk[2], kk[3]); CEU(kk[4], kk[5]); CEU(kk[6], kk[7]);
  }
}

// sort4 + guarded halver (R17-validated).
__device__ __forceinline__ void topk8_batch4(unsigned (&kk)[KK2],
                                             unsigned b0, unsigned b1,
                                             unsigned b2, unsigned b3) {
  CEU(b0, b1); CEU(b2, b3); CEU(b0, b2); CEU(b1, b3); CEU(b1, b2);
  if (b0 < kk[7]) {
    kk[4] = kk[4] < b3 ? kk[4] : b3;
    kk[5] = kk[5] < b2 ? kk[5] : b2;
    kk[6] = kk[6] < b1 ? kk[6] : b1;
    kk[7] = kk[7] < b0 ? kk[7] : b0;
    CEU(kk[0], kk[4]); CEU(kk[1], kk[5]); CEU(kk[2], kk[6]); CEU(kk[3], kk[7]);
    CEU(kk[0], kk[2]); CEU(kk[1], kk[3]); CEU(kk[4], kk[6]); CEU(kk[5], kk[7]);
    CEU(kk[0], kk[1]); CEU(kk[2], kk[3]); CEU(kk[4], kk[5]); CEU(kk[6], kk[7]);
  }
}

// lexicographic (d, idx) insert — exact fp32 merging.
template <int K>
__device__ __forceinline__ void ins_lex(float (&kf)[K], int (&ki)[K], float v, int j) {
  bool ins = (v < kf[K - 1]) || (v == kf[K - 1] && j < ki[K - 1]);
  if (ins) {
    kf[K - 1] = v; ki[K - 1] = j;
    #pragma unroll
    for (int p = K - 1; p > 0; --p) {
      float fa = kf[p - 1], fb = kf[p];
      int   ia = ki[p - 1], ib = ki[p];
      bool sw = (fb < fa) || (fb == fa && ib < ia);
      kf[p - 1] = sw ? fb : fa; ki[p - 1] = sw ? ib : ia;
      kf[p]     = sw ? fa : fb; ki[p]     = sw ? ia : ib;
    }
  }
}

__device__ __forceinline__ unsigned short bf16_rn(float x) {
  unsigned int u = __float_as_uint(x);
  unsigned int r = u + 0x7fffu + ((u >> 16) & 1u);
  return (unsigned short)(r >> 16);
}

// ---------------------------------------------------------------- pack x
__global__ void pack_x_kernel(const float* __restrict__ x, float4* __restrict__ x4) {
  int i = blockIdx.x * blockDim.x + threadIdx.x;
  if (i < NPTS) {
    float a = x[3 * i], b = x[3 * i + 1], c = x[3 * i + 2];
    x4[i] = make_float4(a, b, c, a * a + b * b + c * c);
  }
}

// ---------------------------------------------------------------- merged weight prep
__global__ void prep_weights_kernel(
    const float* __restrict__ W2a, const float* __restrict__ W1b,
    const float* __restrict__ W2b,
    unsigned short* __restrict__ WcFhi, unsigned short* __restrict__ WcFlo,
    unsigned short* __restrict__ W1bFhi, unsigned short* __restrict__ W1bFlo,
    unsigned short* __restrict__ W2Fhi, unsigned short* __restrict__ W2Flo) {
  const int blk = blockIdx.x;
  const int tid = threadIdx.x;
  if (blk < 256) {
    int idx = blk * 256 + tid;
    int k = idx >> 9, c = idx & 511;
    float wh = W2a[(size_t)(HIDC + k) * OUTC2 + (c & 255)];
    float w = (c < OUTC2) ? (W2a[(size_t)k * OUTC2 + c] - wh) : wh;
    unsigned short hi = bf16_rn(w);
    float fh = __uint_as_float(((unsigned int)hi) << 16);
    unsigned short lo = bf16_rn(w - fh);
    const int nt = c >> 4, ct = c & 15;
    const int s = k >> 5, kg = (k >> 3) & 3, e = k & 7;
    const size_t fidx = ((size_t)(s * 32 + nt) * 64 + (kg * 16 + ct)) * 8 + e;
    WcFhi[fidx] = hi;
    WcFlo[fidx] = lo;
  } else if (blk < 384) {
    if (tid < HIDC) {
      const int c = blk - 256;
      const int k = tid;
      float w = W1b[(size_t)k * HIDC + c];
      unsigned short hi = bf16_rn(w);
      float fh = __uint_as_float(((unsigned int)hi) << 16);
      unsigned short lo = bf16_rn(w - fh);
      const int nt = c >> 4, ct = c & 15;
      const int s = k >> 5, kg = (k >> 3) & 3, e = k & 7;
      const size_t idx = ((size_t)(s * 8 + nt) * 64 + (kg * 16 + ct)) * 8 + e;
      W1bFhi[idx] = hi;
      W1bFlo[idx] = lo;
    }
  } else {
    const int c = blk - 384;
    const int k = tid;
    float w = W2b[(size_t)k * OUTC2 + c];
    unsigned short hi = bf16_rn(w);
    float fh = __uint_as_float(((unsigned int)hi) << 16);
    unsigned short lo = bf16_rn(w - fh);
    const int nt = c >> 4, ct = c & 15;
    const int s  = k >> 5, kg = (k >> 3) & 3, e = k & 7;
    const size_t idx = ((size_t)(s * 16 + nt) * 64 + (kg * 16 + ct)) * 8 + e;
    W2Fhi[idx] = hi;
    W2Flo[idx] = lo;
  }
}

// ---------------------------------------------------------------- KNN1 (C=3, K=16) — R17-validated (batch4, 2 q/wave)
__global__ __launch_bounds__(256) void knn3_kernel(const float4* __restrict__ X4,
                                                   int* __restrict__ idx_out) {
  const int tid  = threadIdx.x;
  const int lane = tid & 63;
  const int wv   = __builtin_amdgcn_readfirstlane(tid >> 6);
  const int qA   = blockIdx.x * 8 + wv * 2;
  const int qB   = qA + 1;

  const float4 qa = X4[qA];
  const float4 qb = X4[qB];

  unsigned kkA[KK2], kkB[KK2];
  #pragma unroll
  for (int k = 0; k < KK2; ++k) { kkA[k] = 0xFFFFFFFFu; kkB[k] = 0xFFFFFFFFu; }

  for (int c = 0; c < NPTS / 256; ++c) {
    const int j = c * 256 + lane * 4;
    float4 p[4];
    #pragma unroll
    for (int t = 0; t < 4; ++t) p[t] = X4[j + t];

    unsigned ka[4], kb[4];
    #pragma unroll
    for (int t = 0; t < 4; ++t) {
      float dA = fmaxf(qa.w + p[t].w - 2.f * (qa.x * p[t].x + qa.y * p[t].y + qa.z * p[t].z), 0.f);
      float dB = fmaxf(qb.w + p[t].w - 2.f * (qb.x * p[t].x + qb.y * p[t].y + qb.z * p[t].z), 0.f);
      ka[t] = (__float_as_uint(dA) & 0xFFFFE000u) | (unsigned)(j + t);
      kb[t] = (__float_as_uint(dB) & 0xFFFFE000u) | (unsigned)(j + t);
      if (j + t == qA) ka[t] = 0xFFFFFFFFu;
      if (j + t == qB) kb[t] = 0xFFFFFFFFu;
    }
    topk8_batch4(kkA, ka[0], ka[1], ka[2], ka[3]);
    topk8_batch4(kkB, kb[0], kb[1], kb[2], kb[3]);
  }

  // exact fp32 rescore of kept candidates, per query
  float kfA[KK2], kfB[KK2]; int kjA[KK2], kjB[KK2];
  #pragma unroll
  for (int k = 0; k < KK2; ++k) {
    kfA[k] = INFINITY; kjA[k] = 0x7fffffff;
    kfB[k] = INFINITY; kjB[k] = 0x7fffffff;
  }
  #pragma unroll
  for (int k = 0; k < KK2; ++k) {
    int j = (int)(kkA[k] & 0x1FFFu);
    float4 pj = X4[j];
    float d = qa.w + pj.w - 2.f * (qa.x * pj.x + qa.y * pj.y + qa.z * pj.z);
    if (kkA[k] == 0xFFFFFFFFu) { d = INFINITY; j = 0x7fffffff; }
    ins_lex<KK2>(kfA, kjA, d, j);
  }
  #pragma unroll
  for (int k = 0; k < KK2; ++k) {
    int j = (int)(kkB[k] & 0x1FFFu);
    float4 pj = X4[j];
    float d = qb.w + pj.w - 2.f * (qb.x * pj.x + qb.y * pj.y + qb.z * pj.z);
    if (kkB[k] == 0xFFFFFFFFu) { d = INFINITY; j = 0x7fffffff; }
    ins_lex<KK2>(kfB, kjB, d, j);
  }

  // heads-merge: 16 pops of wave-wide lex-argmin; query A then query B
  #pragma unroll
  for (int k = 0; k < KK1; ++k) {
    float mf = kfA[0]; int mj = kjA[0];
    #pragma unroll
    for (int m = 1; m <= 32; m <<= 1) {
      float of = __shfl_xor(mf, m, 64);
      int   oj = __shfl_xor(mj, m, 64);
      bool g = (of < mf) || (of == mf && oj < mj);
      mf = g ? of : mf; mj = g ? oj : mj;
    }
    const bool won = (kfA[0] == mf) && (kjA[0] == mj);
    if (won) {
      idx_out[(size_t)qA * KK1 + k] = mj;
      #pragma unroll
      for (int p = 0; p < KK2 - 1; ++p) { kfA[p] = kfA[p + 1]; kjA[p] = kjA[p + 1]; }
      kfA[KK2 - 1] = INFINITY; kjA[KK2 - 1] = 0x7fffffff;
    }
  }
  #pragma unroll
  for (int k = 0; k < KK1; ++k) {
    float mf = kfB[0]; int mj = kjB[0];
    #pragma unroll
    for (int m = 1; m <= 32; m <<= 1) {
      float of = __shfl_xor(mf, m, 64);
      int   oj = __shfl_xor(mj, m, 64);
      bool g = (of < mf) || (of == mf && oj < mj);
      mf = g ? of : mf; mj = g ? oj : mj;
    }
    const bool won = (kfB[0] == mf) && (kjB[0] == mj);
    if (won) {
      idx_out[(size_t)qB * KK1 + k] = mj;
      #pragma unroll
      for (int p = 0; p < KK2 - 1; ++p) { kfB[p] = kfB[p + 1]; kjB[p] = kjB[p + 1]; }
      kfB[KK2 - 1] = INFINITY; kjB[KK2 - 1] = 0x7fffffff;
    }
  }
}

// ---------------------------------------------------------------- EdgeConv 1 — MFMA stage-2 (R16-validated)
__global__ __launch_bounds__(512) void edgeconv1_kernel(
    const float* __restrict__ X, const int* __restrict__ knn,
    const float* __restrict__ W1, const float* __restrict__ b1,
    const unsigned short* __restrict__ W1bFhi, const unsigned short* __restrict__ W1bFlo,
    const float* __restrict__ b2,
    float* __restrict__ H, unsigned short* __restrict__ Hhi,
    unsigned short* __restrict__ Hlo, float* __restrict__ SQ2) {
  __shared__ __align__(16) unsigned short Ghi[128 * HIDC];
  __shared__ __align__(16) unsigned short Glo[128 * HIDC];
  __shared__ __align__(16) unsigned short Bs[2][2][4096];
  __shared__ float xjs[8][KK1][3];
  __shared__ float xis[8][3];
  const int tid  = threadIdx.x;
  const int lane = tid & 63;
  const int wv   = __builtin_amdgcn_readfirstlane(tid >> 6);
  const int p    = blockIdx.x * 8 + wv;

  if (lane < KK1) {
    int j = knn[p * KK1 + lane];
    xjs[wv][lane][0] = X[3 * j]; xjs[wv][lane][1] = X[3 * j + 1]; xjs[wv][lane][2] = X[3 * j + 2];
  } else if (lane < KK1 + 3) {
    xis[wv][lane - KK1] = X[3 * p + lane - KK1];
  }
  __syncthreads();

  {
    const int ch0 = lane * 2;
    float2 w1r[6];
    #pragma unroll
    for (int c = 0; c < 6; ++c)
      w1r[c] = make_float2(W1[c * HIDC + ch0], W1[c * HIDC + ch0 + 1]);
    const float2 b1v = make_float2(b1[ch0], b1[ch0 + 1]);
    const float xi0 = xis[wv][0], xi1 = xis[wv][1], xi2 = xis[wv][2];
    const float base0 = b1v.x + xi0 * w1r[0].x + xi1 * w1r[1].x + xi2 * w1r[2].x;
    const float base1 = b1v.y + xi0 * w1r[0].y + xi1 * w1r[1].y + xi2 * w1r[2].y;
    #pragma unroll
    for (int e = 0; e < KK1; ++e) {
      float dx = xjs[wv][e][0] - xi0, dy = xjs[wv][e][1] - xi1, dz = xjs[wv][e][2] - xi2;
      float v0 = fmaxf(base0 + dx * w1r[3].x + dy * w1r[4].x + dz * w1r[5].x, 0.f);
      float v1 = fmaxf(base1 + dx * w1r[3].y + dy * w1r[4].y + dz * w1r[5].y, 0.f);
      unsigned short h0 = bf16_rn(v0), h1s = bf16_rn(v1);
      unsigned short l0 = bf16_rn(v0 - __uint_as_float(((unsigned)h0) << 16));
      unsigned short l1 = bf16_rn(v1 - __uint_as_float(((unsigned)h1s) << 16));
      const int r   = wv * 16 + e;
      const int off = r * 256 + (((ch0 >> 3) ^ (r & 7)) << 4) + ((ch0 & 7) << 1);
      *(ushort2*)((char*)Ghi + off) = make_ushort2(h0, h1s);
      *(ushort2*)((char*)Glo + off) = make_ushort2(l0, l1);
    }
  }

  auto stageB = [&](int buf, int s) {
    const size_t go = (size_t)s * 4096 + (size_t)wv * 512 + (size_t)lane * 8;
    async_ld16((char*)&Bs[buf][0][0] + wv * 1024, W1bFhi + go);
    async_ld16((char*)&Bs[buf][1][0] + wv * 1024, W1bFlo + go);
  };

  stageB(0, 0);
  asm volatile("s_waitcnt vmcnt(0)" ::: "memory");
  __syncthreads();

  const int col = lane & 15;
  const int kg  = lane >> 4;
  const int ar  = wv * 16 + col;
  const int abase = ar * 256;

  f32x4 acc[8];
  #pragma unroll
  for (int n = 0; n < 8; ++n) acc[n] = (f32x4){0.f, 0.f, 0.f, 0.f};

  for (int s = 0; s < 4; ++s) {
    const int cur = s & 1;
    if (s + 1 < 4) stageB(cur ^ 1, s + 1);
    const int asl = (((s * 4 + kg) ^ (ar & 7)) << 4);
    short8 ghi = *(const short8*)((const char*)Ghi + abase + asl);
    short8 glo = *(const short8*)((const char*)Glo + abase + asl);
    #pragma unroll
    for (int n = 0; n < 8; ++n) {
      const int bo = (n * 64 + lane) * 16;
      short8 bhi = *(const short8*)((const char*)&Bs[cur][0][0] + bo);
      short8 blo = *(const short8*)((const char*)&Bs[cur][1][0] + bo);
      acc[n] = mfma16(ghi, bhi, acc[n]);
      acc[n] = mfma16(ghi, blo, acc[n]);
      acc[n] = mfma16(glo, bhi, acc[n]);
    }
    asm volatile("s_waitcnt vmcnt(0)" ::: "memory");
    __syncthreads();
  }

  float sq = 0.f;
  float hv[8];
  #pragma unroll
  for (int n = 0; n < 8; ++n) {
    float m = fmaxf(fmaxf(acc[n][0], acc[n][1]), fmaxf(acc[n][2], acc[n][3]));
    m = fmaxf(m, __shfl_xor(m, 16, 64));
    m = fmaxf(m, __shfl_xor(m, 32, 64));
    m += b2[n * 16 + col];
    hv[n] = m;
    sq += m * m;
  }
  if (kg == 0) {
    #pragma unroll
    for (int n = 0; n < 8; ++n) {
      const int ch = n * 16 + col;
      H[(size_t)p * HIDC + ch] = hv[n];
      unsigned short hb = bf16_rn(hv[n]);
      float fh = __uint_as_float(((unsigned)hb) << 16);
      Hhi[(size_t)p * HIDC + ch] = hb;
      Hlo[(size_t)p * HIDC + ch] = bf16_rn(hv[n] - fh);
    }
  }
  #pragma unroll
  for (int m2 = 1; m2 <= 8; m2 <<= 1) sq += __shfl_xor(sq, m2, 64);
  if (lane == 0) SQ2[p] = sq;
}

// ---------------------------------------------------------------- PQ = H @ Wc via MFMA (R16-validated)
__global__ __launch_bounds__(512) void gemm_pq_kernel(
    const unsigned short* __restrict__ Hhi, const unsigned short* __restrict__ Hlo,
    const unsigned short* __restrict__ WcFhi, const unsigned short* __restrict__ WcFlo,
    const float* __restrict__ b1, float* __restrict__ PQ) {
  __shared__ __align__(16) unsigned short Ahi[64 * HIDC];
  __shared__ __align__(16) unsigned short Alo[64 * HIDC];
  __shared__ __align__(16) unsigned short Bsl[2][2][8192];
  const int tid  = threadIdx.x;
  const int lane = tid & 63;
  const int wv   = __builtin_amdgcn_readfirstlane(tid >> 6);
  const int mb   = blockIdx.x >> 1;
  const int ns   = blockIdx.x & 1;
  const int r0   = mb * 64;

  #pragma unroll
  for (int i = 0; i < 2; ++i) {
    const int srow = wv * 8 + i * 4 + (lane >> 4);
    const int sslt = (lane & 15) ^ (srow & 7);
    const size_t go = (size_t)(r0 + srow) * HIDC + sslt * 8;
    async_ld16((char*)Ahi + (wv * 8 + i * 4) * 256, Hhi + go);
    async_ld16((char*)Alo + (wv * 8 + i * 4) * 256, Hlo + go);
  }
  auto stageB = [&](int buf, int s) {
    #pragma unroll
    for (int i = 0; i < 2; ++i) {
      const size_t go = (size_t)(s * 32 + ns * 16) * 512 + (size_t)wv * 1024 + i * 512 + lane * 8;
      async_ld16((char*)&Bsl[buf][0][0] + wv * 2048 + i * 1024, WcFhi + go);
      async_ld16((char*)&Bsl[buf][1][0] + wv * 2048 + i * 1024, WcFlo + go);
    }
  };
  stageB(0, 0);
  asm volatile("s_waitcnt vmcnt(0)" ::: "memory");
  __syncthreads();

  const int col = lane & 15;
  const int kg  = lane >> 4;
  const int mt  = wv & 3;
  const int nh  = wv >> 2;
  const int ar  = mt * 16 + col;
  const int abase = ar * 256;

  f32x4 acc[8];
  #pragma unroll
  for (int n = 0; n < 8; ++n) acc[n] = (f32x4){0.f, 0.f, 0.f, 0.f};

  for (int s = 0; s < 4; ++s) {
    const int cur = s & 1;
    if (s + 1 < 4) stageB(cur ^ 1, s + 1);
    const int asl = (((s * 4 + kg) ^ (ar & 7)) << 4);
    short8 ahi8 = *(const short8*)((const char*)Ahi + abase + asl);
    short8 alo8 = *(const short8*)((const char*)Alo + abase + asl);
    #pragma unroll
    for (int n = 0; n < 8; ++n) {
      const int ntl = nh * 8 + n;
      const int bo = (ntl * 64 + lane) * 16;
      short8 bhi = *(const short8*)((const char*)&Bsl[cur][0][0] + bo);
      short8 blo = *(const short8*)((const char*)&Bsl[cur][1][0] + bo);
      acc[n] = mfma16(ahi8, bhi, acc[n]);
      acc[n] = mfma16(ahi8, blo, acc[n]);
      acc[n] = mfma16(alo8, bhi, acc[n]);
    }
    asm volatile("s_waitcnt vmcnt(0)" ::: "memory");
    __syncthreads();
  }

  #pragma unroll
  for (int n = 0; n < 8; ++n) {
    const int cg = ns * 256 + (nh * 8 + n) * 16 + col;
    const float bb = (ns == 0) ? b1[cg] : 0.f;
    #pragma unroll
    for (int r = 0; r < 4; ++r) {
      const int row = r0 + mt * 16 + kg * 4 + r;
      PQ[(size_t)row * PQC + cg] = acc[n][r] + bb;
    }
  }
}

// ---------------------------------------------------------------- KNN2 filter (32-row chunks, R19-validated)
constexpr int JSPLIT = 16;
constexpr int JPB2   = NPTS / JSPLIT;
constexpr int NCH2   = JPB2 / 32;
constexpr int CPQ    = JSPLIT * KK2;

__global__ __launch_bounds__(256) void knn128_filter_kernel(
    const unsigned short* __restrict__ Hhi, const unsigned short* __restrict__ Hlo,
    const float* __restrict__ SQ, unsigned* __restrict__ pk2) {
  __shared__ __align__(16) unsigned short As[2][2][32 * HIDC];
  const int tid  = threadIdx.x;
  const int lane = tid & 63;
  const int wv   = __builtin_amdgcn_readfirstlane(tid >> 6);
  const int qb   = blockIdx.x >> 4;
  const int js   = blockIdx.x & 15;
  const int col  = lane & 15;
  const int kg   = lane >> 4;
  const int qg   = qb * 64 + wv * 16 + col;

  short8 qhi[4], qlo[4];
  #pragma unroll
  for (int s = 0; s < 4; ++s) {
    const size_t o = (size_t)qg * HIDC + s * 32 + kg * 8;
    qhi[s] = *reinterpret_cast<const short8*>(Hhi + o);
    qlo[s] = *reinterpret_cast<const short8*>(Hlo + o);
  }
  const float sqq = SQ[qg];

  unsigned kk[KK2];
  #pragma unroll
  for (int k = 0; k < KK2; ++k) kk[k] = 0xFFFFFFFFu;

  const int jbase = js * JPB2;

  auto stage = [&](int buf, int ch) {
    #pragma unroll
    for (int i = 0; i < 2; ++i) {
      const int srow = 8 * wv + i * 4 + (lane >> 4);
      const int sslt = (lane & 15) ^ (srow & 7);
      const size_t gofs = (size_t)(jbase + ch * 32 + srow) * HIDC + sslt * 8;
      async_ld16((char*)&As[buf][0][0] + (8 * wv + i * 4) * 256, Hhi + gofs);
      async_ld16((char*)&As[buf][1][0] + (8 * wv + i * 4) * 256, Hlo + gofs);
    }
  };

  stage(0, 0);
  asm volatile("s_waitcnt vmcnt(0)" ::: "memory");
  __syncthreads();

  for (int ch = 0; ch < NCH2; ++ch) {
    const int cur = ch & 1;
    if (ch + 1 < NCH2) stage(cur ^ 1, ch + 1);

    #pragma unroll
    for (int t = 0; t < 2; ++t) {
      const int jb = jbase + ch * 32 + t * 16;
      short8 ahi[4], alo[4];
      const int rowb = (t * 16 + col) * 256;
      #pragma unroll
      for (int s = 0; s < 4; ++s) {
        const int sl = ((s * 4 + kg) ^ (col & 7)) * 16;
        ahi[s] = *(const short8*)((const char*)&As[cur][0][0] + rowb + sl);
        alo[s] = *(const short8*)((const char*)&As[cur][1][0] + rowb + sl);
      }
      f32x4 sqjv = *reinterpret_cast<const f32x4*>(SQ + jb + kg * 4);

      f32x4 acc = {0.f, 0.f, 0.f, 0.f};
      #pragma unroll
      for (int s = 0; s < 4; ++s) {
        acc = mfma16(ahi[s], qhi[s], acc);
        acc = mfma16(ahi[s], qlo[s], acc);
        acc = mfma16(alo[s], qhi[s], acc);
      }
      unsigned kb[4];
      #pragma unroll
      for (int r = 0; r < 4; ++r) {
        const int jg = jb + kg * 4 + r;
        float d = fmaxf(sqq + sqjv[r] - 2.f * acc[r], 0.f);
        kb[r] = (__float_as_uint(d) & 0xFFFFE000u) | (unsigned)jg;
        if (jg == qg) kb[r] = 0xFFFFFFFFu;
      }
      topk8_batch4(kk, kb[0], kb[1], kb[2], kb[3]);
    }
    asm volatile("s_waitcnt vmcnt(0)" ::: "memory");
    __syncthreads();
  }

  #pragma unroll
  for (int dlt = 16; dlt <= 32; dlt <<= 1) {
    unsigned ok[KK2];
    #pragma unroll
    for (int k = 0; k < KK2; ++k) ok[k] = __shfl_xor((int)kk[k], dlt, 64);
    topk8_merge_sorted(kk, ok);
  }
  if (lane < 16) {
    const size_t base = (size_t)qg * CPQ + js * KK2;
    #pragma unroll
    for (int k = 0; k < KK2; ++k) pk2[base + k] = kk[k];
  }
}

// ---------------------------------------------------------------- rescore (R15-validated)
__global__ __launch_bounds__(256) void knn_rescore_kernel(
    const float* __restrict__ H, const float* __restrict__ SQ,
    const unsigned* __restrict__ pk2, int* __restrict__ idx_out) {
  __shared__ float qrow[16][HIDC + 4];
  const int tid  = threadIdx.x;
  const int lane = tid & 63;
  const int wv   = tid >> 6;
  const int g    = lane >> 4;
  const int sl   = lane & 15;
  const int q0   = blockIdx.x * 16;
  const int qloc = wv * 4 + g;
  const int q    = q0 + qloc;

  for (int u = tid; u < 16 * 32; u += 256) {
    int r = u >> 5, c4 = u & 31;
    *(f32x4*)&qrow[r][c4 * 4] = *(const f32x4*)&H[(size_t)(q0 + r) * HIDC + c4 * 4];
  }
  __syncthreads();

  unsigned kreg[KK2];
  {
    const unsigned* src = pk2 + (size_t)q * CPQ + sl * KK2;
    uint4 a = *(const uint4*)(src);
    uint4 b = *(const uint4*)(src + 4);
    kreg[0] = a.x; kreg[1] = a.y; kreg[2] = a.z; kreg[3] = a.w;
    kreg[4] = b.x; kreg[5] = b.y; kreg[6] = b.z; kreg[7] = b.w;
  }

  unsigned ckey = 0xFFFFFFFFu;
  #pragma unroll
  for (int t = 0; t < 16; ++t) {
    unsigned m = kreg[0];
    #pragma unroll
    for (int mm = 1; mm <= 8; mm <<= 1) {
      unsigned o = (unsigned)__shfl_xor((int)m, mm, 64);
      m = o < m ? o : m;
    }
    if (t == sl) ckey = m;
    const bool won = (kreg[0] == m);
    if (won) {
      #pragma unroll
      for (int p = 0; p < KK2 - 1; ++p) kreg[p] = kreg[p + 1];
      kreg[KK2 - 1] = 0xFFFFFFFFu;
    }
  }
  const int ci = (int)(ckey & 0x1FFFu);

  const float* crow = H + (size_t)ci * HIDC;
  float dot = 0.f;
  #pragma unroll 8
  for (int c4 = 0; c4 < HIDC / 4; ++c4) {
    f32x4 qv = *(const f32x4*)&qrow[qloc][c4 * 4];
    f32x4 cv = *(const f32x4*)(crow + c4 * 4);
    dot += qv[0] * cv[0] + qv[1] * cv[1] + qv[2] * cv[2] + qv[3] * cv[3];
  }
  float d = SQ[q] + SQ[ci] - 2.f * dot;

  float kf[KK2]; int ki[KK2];
  kf[0] = d; ki[0] = ci;
  #pragma unroll
  for (int k = 1; k < KK2; ++k) { kf[k] = INFINITY; ki[k] = 0x7fffffff; }
  #pragma unroll
  for (int dlt = 1; dlt <= 8; dlt <<= 1) {
    float of[KK2]; int oi[KK2];
    #pragma unroll
    for (int k = 0; k < KK2; ++k) { of[k] = __shfl_xor(kf[k], dlt, 64); oi[k] = __shfl_xor(ki[k], dlt, 64); }
    #pragma unroll
    for (int k = 0; k < KK2; ++k) ins_lex<KK2>(kf, ki, of[k], oi[k]);
  }
  if (sl == 0) {
    #pragma unroll
    for (int k = 0; k < KK2; ++k) idx_out[(size_t)q * KK2 + k] = ki[k];
  }
}

// ---------------------------------------------------------------- EdgeConv 2 — MFMA, LDS-staged B (R14-validated)
__global__ __launch_bounds__(512) void edgeconv2_kernel(
    const float* __restrict__ PQ, const int* __restrict__ knn,
    const unsigned short* __restrict__ W2Fhi, const unsigned short* __restrict__ W2Flo,
    const float* __restrict__ b2, float* __restrict__ Out) {
  __shared__ __align__(16) unsigned short Ghi[64 * OUTC2];
  __shared__ __align__(16) unsigned short Glo[64 * OUTC2];
  __shared__ __align__(16) unsigned short Bs[2][2][8192];
  const int tid  = threadIdx.x;
  const int lane = tid & 63;
  const int wv   = __builtin_amdgcn_readfirstlane(tid >> 6);
  const int p_base = blockIdx.x * 8;

  {
    const int p   = p_base + wv;
    const int ch0 = lane * 4;
    f32x4 pv = *(const f32x4*)&PQ[(size_t)p * PQC + ch0];
    #pragma unroll
    for (int e = 0; e < KK2; ++e) {
      const int j = knn[p * KK2 + e];
      f32x4 qv = *(const f32x4*)&PQ[(size_t)j * PQC + OUTC2 + ch0];
      unsigned short hb[4], lb[4];
      #pragma unroll
      for (int c = 0; c < 4; ++c) {
        float g = fmaxf(pv[c] + qv[c], 0.f);
        hb[c] = bf16_rn(g);
        float fh = __uint_as_float(((unsigned int)hb[c]) << 16);
        lb[c] = bf16_rn(g - fh);
      }
      const int r   = wv * 8 + e;
      const int off = r * 512 + (((ch0 >> 3) ^ (r & 7)) << 4) + ((ch0 & 7) << 1);
      *(ushort4*)((char*)Ghi + off) = make_ushort4(hb[0], hb[1], hb[2], hb[3]);
      *(ushort4*)((char*)Glo + off) = make_ushort4(lb[0], lb[1], lb[2], lb[3]);
    }
  }

  auto stageB = [&](int buf, int s) {
    #pragma unroll
    for (int i = 0; i < 2; ++i) {
      const size_t go = (size_t)s * 8192 + (size_t)(wv * 2 + i) * 512 + (size_t)lane * 8;
      async_ld16((char*)&Bs[buf][0][0] + (wv * 2 + i) * 1024, W2Fhi + go);
      async_ld16((char*)&Bs[buf][1][0] + (wv * 2 + i) * 1024, W2Flo + go);
    }
  };

  stageB(0, 0);
  asm volatile("s_waitcnt vmcnt(0)" ::: "memory");
  __syncthreads();

  const int col = lane & 15;
  const int kg  = lane >> 4;
  const int mt  = wv & 3;
  const int nh  = wv >> 2;
  const int ar  = mt * 16 + col;
  const int abase = ar * 512;

  f32x4 acc[8];
  #pragma unroll
  for (int n = 0; n < 8; ++n) acc[n] = (f32x4){0.f, 0.f, 0.f, 0.f};

  for (int s = 0; s < 8; ++s) {
    const int cur = s & 1;
    if (s + 1 < 8) stageB(cur ^ 1, s + 1);

    const int asl = (((s * 4 + kg) ^ (ar & 7)) << 4);
    short8 ghi = *(const short8*)((const char*)Ghi + abase + asl);
    short8 glo = *(const short8*)((const char*)Glo + abase + asl);
    #pragma unroll
    for (int n = 0; n < 8; ++n) {
      const int nt = nh * 8 + n;
      const int bo = (nt * 64 + lane) * 16;
      short8 bhi = *(const short8*)((const char*)&Bs[cur][0][0] + bo);
      short8 blo = *(const short8*)((const char*)&Bs[cur][1][0] + bo);
      acc[n] = mfma16(ghi, bhi, acc[n]);
      acc[n] = mfma16(ghi, blo, acc[n]);
      acc[n] = mfma16(glo, bhi, acc[n]);
    }
    asm volatile("s_waitcnt vmcnt(0)" ::: "memory");
    __syncthreads();
  }

  const int pt = p_base + mt * 2 + (kg >> 1);
  #pragma unroll
  for (int n = 0; n < 8; ++n) {
    float m = fmaxf(fmaxf(acc[n][0], acc[n][1]), fmaxf(acc[n][2], acc[n][3]));
    m = fmaxf(m, __shfl_xor(m, 16, 64));
    if ((kg & 1) == 0) {
      const int ncol = nh * 128 + n * 16 + col;
      Out[(size_t)pt * OUTC2 + ncol] = m + b2[ncol];
    }
  }
}

// ---------------------------------------------------------------- launch
extern "C" void kernel_launch(void* const* d_in, const int* in_sizes, int n_in,
                              void* d_out, int out_size, void* d_ws, size_t ws_size,
                              hipStream_t stream) {
  const float* x   = (const float*)d_in[0];
  const float* W1a = (const float*)d_in[1];
  const float* b1a = (const float*)d_in[2];
  const float* W1b = (const float*)d_in[3];
  const float* b1b = (const float*)d_in[4];
  const float* W2a = (const float*)d_in[5];
  const float* b2a = (const float*)d_in[6];
  const float* W2b = (const float*)d_in[7];
  const float* b2b = (const float*)d_in[8];
  float* out = (float*)d_out;

  float* h    = (float*)d_ws;                       // 4 MB
  float* sq2  = h + (size_t)NPTS * HIDC;
  int*   idx1 = (int*)(sq2 + NPTS);
  int*   idx2 = idx1 + (size_t)NPTS * KK1;
  unsigned short* Hhi = (unsigned short*)(idx2 + (size_t)NPTS * KK2);  // 2 MB
  unsigned short* Hlo = Hhi + (size_t)NPTS * HIDC;                     // 2 MB
  unsigned* pk2 = (unsigned*)(Hlo + (size_t)NPTS * HIDC);              // 4 MB
  float* PQ   = (float*)(pk2 + (size_t)NPTS * CPQ); // 16 MB
  unsigned short* W2Fhi = (unsigned short*)(PQ + (size_t)NPTS * PQC);  // 128 KB
  unsigned short* W2Flo = W2Fhi + (size_t)OUTC2 * OUTC2;               // 128 KB
  unsigned short* WcFhi = W2Flo + (size_t)OUTC2 * OUTC2;               // 128 KB
  unsigned short* WcFlo = WcFhi + (size_t)HIDC * PQC;                  // 128 KB
  unsigned short* W1bFhi = WcFlo + (size_t)HIDC * PQC;                 // 32 KB
  unsigned short* W1bFlo = W1bFhi + (size_t)HIDC * HIDC;               // 32 KB
  // x4 aliases h's first 128KB: knn3 finishes before edgeconv1 writes h.
  float4* x4 = (float4*)h;

  pack_x_kernel<<<(NPTS + 255) / 256, 256, 0, stream>>>(x, x4);
  prep_weights_kernel<<<640, 256, 0, stream>>>(W2a, W1b, W2b,
                                               WcFhi, WcFlo, W1bFhi, W1bFlo,
                                               W2Fhi, W2Flo);
  knn3_kernel<<<NPTS / 8, 256, 0, stream>>>(x4, idx1);
  edgeconv1_kernel<<<NPTS / 8, 512, 0, stream>>>(x, idx1, W1a, b1a,
                                                 W1bFhi, W1bFlo, b1b,
                                                 h, Hhi, Hlo, sq2);
  gemm_pq_kernel<<<(NPTS / 64) * 2, 512, 0, stream>>>(Hhi, Hlo, WcFhi, WcFlo, b2a, PQ);
  knn128_filter_kernel<<<(NPTS / 64) * JSPLIT, 256, 0, stream>>>(Hhi, Hlo, sq2, pk2);
  knn_rescore_kernel<<<NPTS / 16, 256, 0, stream>>>(h, sq2, pk2, idx2);
  edgeconv2_kernel<<<NPTS / 8, 512, 0, stream>>>(PQ, idx2, W2Fhi, W2Flo, b2b, out);
}